// Round 1
// baseline (3818.952 us; speedup 1.0000x reference)
//
#include <hip/hip_runtime.h>
#include <cmath>

#define HTOT  590
#define BATCH 4096
#define VOCAB 8192

// ---------------- workspace layout (float units) ----------------
constexpr size_t SZ_G    = 5ull*VOCAB*224;        // 9,175,040  g-table
constexpr size_t OFF_G   = 0;
constexpr size_t SZ_P    = 31ull*BATCH*64;        // 8,126,464  BN partials
constexpr size_t OFF_PA  = OFF_G  + SZ_G;
constexpr size_t OFF_PB  = OFF_PA + SZ_P;
constexpr size_t OFF_BN1 = OFF_PB + SZ_P;         // 320
constexpr size_t OFF_BNP = OFF_BN1 + 320;         // 320
constexpr size_t SZ_Z    = 4096ull*1920;
constexpr size_t OFF_Z   = OFF_BNP + 320;
constexpr size_t SZ_Y    = 4096ull*2048;
constexpr size_t OFF_Y   = OFF_Z  + SZ_Z;
constexpr size_t OFF_Z2  = OFF_Y  + SZ_Y;
constexpr size_t OFF_CP  = OFF_Z2 + SZ_Y;         // 2048*32 doubles = 131072 floats
constexpr size_t OFF_BNF1= OFF_CP + 131072;
constexpr size_t OFF_BNF2= OFF_BNF1 + 4096;
// z3 reuses OFF_G (8,388,608 <= 9,175,040)

__device__ __forceinline__ float qw(float w) {
  return rintf(fminf(fmaxf(w, -1.f), 1.f));      // quant_signed(clip(w), 2): round-half-even
}

// ---------------- g-table: g[slice][v][k*32+f] = sum_c emb[v][c]*w[f][c][k] ----------------
__global__ __launch_bounds__(256) void k_gtable(const float* __restrict__ emb,
                                                const float* __restrict__ convw,
                                                float* __restrict__ g)
{
  const int slice = blockIdx.x >> 8;           // 5 slices x 256 vblocks
  const int v0 = (blockIdx.x & 255) * 32;
  const int tid = threadIdx.x;
  __shared__ float wsb[32*225];                // padded: f*225 + c*7 + k
  __shared__ float eb[32];
  const float* wsl = convw + slice*(32*32*7);
  for (int j = tid; j < 32*224; j += 256) {
    const int f = j / 224, r = j - f*224;
    wsb[f*225 + r] = wsl[j];
  }
  const float* esl = emb + (size_t)slice*VOCAB*32;
  float* gsl = g + (size_t)slice*VOCAB*224;
  const int k = tid >> 5, f = tid & 31;
  for (int vi = 0; vi < 32; ++vi) {
    __syncthreads();
    if (tid < 32) eb[tid] = esl[(size_t)(v0+vi)*32 + tid];
    __syncthreads();
    if (tid < 224) {
      float acc = 0.f;
      #pragma unroll 8
      for (int c = 0; c < 32; ++c) acc += eb[c] * wsb[f*225 + c*7 + k];
      gsl[(size_t)(v0+vi)*224 + tid] = acc;
    }
  }
}

// ---------------- pass A: conv via g-table, per-(slice,f) stat partials ----------------
__global__ __launch_bounds__(256) void k_passA(const int* __restrict__ x,
                                               const int* __restrict__ gshift,
                                               const float* __restrict__ g,
                                               float* __restrict__ partials)
{
  const int cid = blockIdx.x;   // 0..30
  const int b   = blockIdx.y;
  int slice, lc, L, pw, sh;
  if      (cid < 1) { slice=0; lc=cid;    L=42;  pw=3;  sh=0; }
  else if (cid < 3) { slice=1; lc=cid-1;  L=78;  pw=6;  sh=0; }
  else if (cid < 7) { slice=2; lc=cid-3;  L=150; pw=12; sh=1; }
  else if (cid <15) { slice=3; lc=cid-7;  L=294; pw=24; sh=1; }
  else              { slice=4; lc=cid-15; L=582; pw=48; sh=1; }
  const int tid = threadIdx.x;
  const int t0 = lc*36;

  __shared__ int   toks[42];
  __shared__ float gsb[42*224];
  __shared__ float red[512];

  if (tid < 42) {
    const int s = sh ? (gshift[b] % pw) : 0;
    int idx = (HTOT - L - s) + t0 + tid;
    if (idx < 0) idx += HTOT;                  // numpy/jax negative-index wrap
    toks[tid] = x[b*HTOT + idx];
  }
  __syncthreads();
  const float* gsl = g + (size_t)slice*VOCAB*224;
  for (int j = tid; j < 42*224; j += 256) {
    const int p = j / 224;
    const int r = j - p*224;
    gsb[j] = gsl[(size_t)toks[p]*224 + r];
  }
  __syncthreads();
  const int f = tid & 31;
  float s1 = 0.f, s2 = 0.f;
  for (int idx = tid; idx < 36*32; idx += 256) {
    const int t = idx >> 5;
    float h = 0.f;
    #pragma unroll
    for (int k = 0; k < 7; ++k) h += gsb[(t+k)*224 + k*32 + f];
    s1 += h; s2 += h*h;
  }
  red[tid] = s1; red[256+tid] = s2;
  __syncthreads();
  if (tid < 32) {
    float a = 0.f, c = 0.f;
    #pragma unroll
    for (int q = 0; q < 8; ++q) { a += red[tid + 32*q]; c += red[256 + tid + 32*q]; }
    int cpb, base;
    switch (slice) {
      case 0: cpb=1;  base=0;        break;
      case 1: cpb=2;  base=BATCH;    break;
      case 2: cpb=4;  base=BATCH*3;  break;
      case 3: cpb=8;  base=BATCH*7;  break;
      default:cpb=16; base=BATCH*15; break;
    }
    const size_t blk = (size_t)base + (size_t)b*cpb + lc;
    float* dst = partials + blk*64 + tid*2;
    dst[0] = a; dst[1] = c;
  }
}

// ---------------- BN stat reduce: partials -> per-(slice,f) {A=g*rstd, B=beta-A*m} ----------------
template<int PASS>
__global__ __launch_bounds__(256) void k_bnreduce(const float* __restrict__ partials,
                                                  const float* __restrict__ gamma,
                                                  const float* __restrict__ beta,
                                                  float* __restrict__ outAB)
{
  const int slice = blockIdx.x >> 5;
  const int f = blockIdx.x & 31;
  int cpb, base; long N;
  if (PASS == 0) {
    switch (slice) {
      case 0: cpb=1;  base=0;        N=(long)BATCH*36;  break;
      case 1: cpb=2;  base=BATCH;    N=(long)BATCH*72;  break;
      case 2: cpb=4;  base=BATCH*3;  N=(long)BATCH*144; break;
      case 3: cpb=8;  base=BATCH*7;  N=(long)BATCH*288; break;
      default:cpb=16; base=BATCH*15; N=(long)BATCH*576; break;
    }
  } else {
    N = (long)BATCH*12;
    switch (slice) {
      case 0: cpb=1;  base=0;        break;
      case 1: cpb=2;  base=BATCH;    break;
      case 2: cpb=4;  base=BATCH*3;  break;
      case 3: cpb=12; base=BATCH*7;  break;
      default:cpb=12; base=BATCH*19; break;
    }
  }
  const long nblk = (long)BATCH*cpb;
  double s1 = 0.0, s2 = 0.0;
  for (long i = threadIdx.x; i < nblk; i += 256) {
    const float* p = partials + ((size_t)base + i)*64 + f*2;
    s1 += (double)p[0]; s2 += (double)p[1];
  }
  __shared__ double r1[256], r2[256];
  r1[threadIdx.x] = s1; r2[threadIdx.x] = s2;
  __syncthreads();
  for (int off = 128; off > 0; off >>= 1) {
    if ((int)threadIdx.x < off) {
      r1[threadIdx.x] += r1[threadIdx.x+off];
      r2[threadIdx.x] += r2[threadIdx.x+off];
    }
    __syncthreads();
  }
  if (threadIdx.x == 0) {
    const double m   = r1[0]/(double)N;
    const double var = r2[0]/(double)N - m*m;
    const float rstd = (float)(1.0/sqrt(var + 1e-5));
    const float gm = gamma[slice*32+f], bt = beta[slice*32+f];
    const float Aa = gm*rstd;
    const float Bb = bt - Aa*(float)m;
    outAB[(slice*32+f)*2]   = Aa;
    outAB[(slice*32+f)*2+1] = Bb;
  }
}

// ---------------- pass B: conv + BN1 + tanh + avgpool -> p, pooled stat partials ----------------
__global__ __launch_bounds__(256) void k_passB(const int* __restrict__ x,
                                               const int* __restrict__ gshift,
                                               const float* __restrict__ g,
                                               const float* __restrict__ bn1,
                                               float* __restrict__ z,
                                               float* __restrict__ partials)
{
  const int cid = blockIdx.x;   // 0..30
  const int b   = blockIdx.y;
  int slice, lc, L, pw, sh, Tt, P;
  if      (cid < 1) { slice=0; lc=cid;    L=42;  pw=3;  sh=0; Tt=36; P=12; }
  else if (cid < 3) { slice=1; lc=cid-1;  L=78;  pw=6;  sh=0; Tt=36; P=6;  }
  else if (cid < 7) { slice=2; lc=cid-3;  L=150; pw=12; sh=1; Tt=36; P=3;  }
  else if (cid <19) { slice=3; lc=cid-7;  L=294; pw=24; sh=1; Tt=24; P=1;  }
  else              { slice=4; lc=cid-19; L=582; pw=48; sh=1; Tt=48; P=1;  }
  const int tid = threadIdx.x;
  const int t0 = lc*Tt;
  const int ntok = Tt + 6;

  __shared__ int   toks[54];
  __shared__ float gsb[54*224];
  __shared__ float th[48*32];
  __shared__ float red[512];

  if (tid < ntok) {
    const int s = sh ? (gshift[b] % pw) : 0;
    int idx = (HTOT - L - s) + t0 + tid;
    if (idx < 0) idx += HTOT;
    toks[tid] = x[b*HTOT + idx];
  }
  __syncthreads();
  const float* gsl = g + (size_t)slice*VOCAB*224;
  const int nstage = ntok*224;
  for (int j = tid; j < nstage; j += 256) {
    const int p = j / 224;
    const int r = j - p*224;
    gsb[j] = gsl[(size_t)toks[p]*224 + r];
  }
  __syncthreads();
  const int f = tid & 31;
  const float A1 = bn1[(slice*32+f)*2];
  const float B1 = bn1[(slice*32+f)*2+1];
  for (int idx = tid; idx < Tt*32; idx += 256) {
    const int t = idx >> 5;
    float h = 0.f;
    #pragma unroll
    for (int k = 0; k < 7; ++k) h += gsb[(t+k)*224 + k*32 + f];
    th[idx] = tanhf(h*A1 + B1);      // idx == t*32 + f
  }
  __syncthreads();
  float sp1 = 0.f, sp2 = 0.f;
  for (int idx = tid; idx < P*32; idx += 256) {
    const int tp = idx >> 5;
    float acc = 0.f;
    for (int j = 0; j < pw; ++j) acc += th[(tp*pw + j)*32 + f];
    const float pv = acc / (float)pw;
    const int t12 = lc*P + tp;
    z[(size_t)b*1920 + slice*384 + f*12 + t12] = pv;
    sp1 += pv; sp2 += pv*pv;
  }
  red[tid] = sp1; red[256+tid] = sp2;
  __syncthreads();
  if (tid < 32) {
    float a = 0.f, c = 0.f;
    #pragma unroll
    for (int q = 0; q < 8; ++q) { a += red[tid + 32*q]; c += red[256 + tid + 32*q]; }
    int cpb, base;
    switch (slice) {
      case 0: cpb=1;  base=0;        break;
      case 1: cpb=2;  base=BATCH;    break;
      case 2: cpb=4;  base=BATCH*3;  break;
      case 3: cpb=12; base=BATCH*7;  break;
      default:cpb=12; base=BATCH*19; break;
    }
    const size_t blk = (size_t)base + (size_t)b*cpb + lc;
    float* dst = partials + blk*64 + tid*2;
    dst[0] = a; dst[1] = c;
  }
}

// ---------------- apply pooled BN to features (in place) ----------------
__global__ __launch_bounds__(256) void k_znorm(float* __restrict__ z,
                                               const float* __restrict__ bnp)
{
  const size_t i = (size_t)blockIdx.x*256 + threadIdx.x;   // exactly 4096*1920
  const int j = (int)(i % 1920);
  const int slice = j / 384;
  const int f = (j - slice*384) / 12;
  const float Aa = bnp[(slice*32+f)*2];
  const float Bb = bnp[(slice*32+f)*2+1];
  z[i] = z[i]*Aa + Bb;
}

// ---------------- fp32 tiled GEMM: C[4096,N] = A[4096,KD] * quant(W[N,KD])^T ----------------
template<int KD>
__global__ __launch_bounds__(256) void k_gemm(const float* __restrict__ A,
                                              const float* __restrict__ W,
                                              float* __restrict__ C, int N)
{
  const int bm = blockIdx.y * 128;
  const int bn = blockIdx.x * 64;
  const int tid = threadIdx.x;
  const int tx = tid & 15, ty = tid >> 4;
  __shared__ float As[16][132];
  __shared__ float Bs[16][68];
  float acc[8][4] = {};
  for (int k0 = 0; k0 < KD; k0 += 16) {
    #pragma unroll
    for (int u = 0; u < 2; ++u) {
      const int id = tid*2 + u;
      const int row = id >> 2, c4 = (id & 3)*4;
      const float4 v = *reinterpret_cast<const float4*>(&A[(size_t)(bm+row)*KD + k0 + c4]);
      As[c4+0][row]=v.x; As[c4+1][row]=v.y; As[c4+2][row]=v.z; As[c4+3][row]=v.w;
    }
    {
      const int row = tid >> 2, c4 = (tid & 3)*4;
      const float4 v = *reinterpret_cast<const float4*>(&W[(size_t)(bn+row)*KD + k0 + c4]);
      Bs[c4+0][row]=qw(v.x); Bs[c4+1][row]=qw(v.y); Bs[c4+2][row]=qw(v.z); Bs[c4+3][row]=qw(v.w);
    }
    __syncthreads();
    #pragma unroll
    for (int kk = 0; kk < 16; ++kk) {
      const float4 a0 = *reinterpret_cast<const float4*>(&As[kk][ty*8]);
      const float4 a1 = *reinterpret_cast<const float4*>(&As[kk][ty*8+4]);
      const float4 bv = *reinterpret_cast<const float4*>(&Bs[kk][tx*4]);
      const float av[8] = {a0.x,a0.y,a0.z,a0.w,a1.x,a1.y,a1.z,a1.w};
      const float bb[4] = {bv.x,bv.y,bv.z,bv.w};
      #pragma unroll
      for (int i = 0; i < 8; ++i)
        #pragma unroll
        for (int j = 0; j < 4; ++j)
          acc[i][j] = fmaf(av[i], bb[j], acc[i][j]);
    }
    __syncthreads();
  }
  #pragma unroll
  for (int i = 0; i < 8; ++i) {
    float4 o; o.x=acc[i][0]; o.y=acc[i][1]; o.z=acc[i][2]; o.w=acc[i][3];
    *reinterpret_cast<float4*>(&C[(size_t)(bm+ty*8+i)*N + bn + tx*4]) = o;
  }
}

// ---------------- column stats (2-stage, deterministic) ----------------
__global__ __launch_bounds__(256) void k_colpart(const float* __restrict__ Y,
                                                 double* __restrict__ part, int N)
{
  const int c0 = blockIdx.x*64;
  const int chunk = blockIdx.y;        // 16 chunks of 256 rows
  const int tid = threadIdx.x;
  const int c = tid & 63, rq = tid >> 6;
  double s1 = 0.0, s2 = 0.0;
  const int rbase = chunk*256;
  for (int r = rbase + rq; r < rbase+256; r += 4) {
    const float v = Y[(size_t)r*N + c0 + c];
    s1 += (double)v; s2 += (double)v*(double)v;
  }
  __shared__ double r1[256], r2[256];
  r1[tid] = s1; r2[tid] = s2;
  __syncthreads();
  if (tid < 64) {
    const double a  = r1[tid]+r1[tid+64]+r1[tid+128]+r1[tid+192];
    const double cc = r2[tid]+r2[tid+64]+r2[tid+128]+r2[tid+192];
    part[(size_t)(c0+c)*32 + chunk*2]     = a;
    part[(size_t)(c0+c)*32 + chunk*2 + 1] = cc;
  }
}

__global__ __launch_bounds__(256) void k_colfinal(const double* __restrict__ part,
                                                  const float* __restrict__ gamma,
                                                  const float* __restrict__ beta,
                                                  float* __restrict__ bnfc, int N)
{
  const int c = blockIdx.x*256 + threadIdx.x;
  if (c >= N) return;
  double s1 = 0.0, s2 = 0.0;
  #pragma unroll
  for (int ch = 0; ch < 16; ++ch) {
    s1 += part[(size_t)c*32 + ch*2];
    s2 += part[(size_t)c*32 + ch*2 + 1];
  }
  const double m   = s1/4096.0;
  const double var = s2/4096.0 - m*m;
  const float rstd = (float)(1.0/sqrt(var + 1e-5));
  const float Aa = gamma[c]*rstd;
  const float Bb = beta[c] - Aa*(float)m;
  bnfc[c*2] = Aa; bnfc[c*2+1] = Bb;
}

// ---------------- BN + hardtanh + 3-bit quantize ----------------
__global__ __launch_bounds__(256) void k_act(const float* __restrict__ Y,
                                             const float* __restrict__ bnfc,
                                             float* __restrict__ Z)
{
  const size_t i4 = (size_t)blockIdx.x*256 + threadIdx.x;  // exactly 2,097,152 float4s
  const int cbase = (int)((i4*4) & 2047);
  const float4 v = *reinterpret_cast<const float4*>(&Y[i4*4]);
  float o[4] = {v.x, v.y, v.z, v.w};
  #pragma unroll
  for (int j = 0; j < 4; ++j) {
    const float Aa = bnfc[(cbase+j)*2], Bb = bnfc[(cbase+j)*2+1];
    float t = o[j]*Aa + Bb;
    t = fminf(fmaxf(t, -1.f), 1.f);
    o[j] = rintf(t*3.f)/3.f;
  }
  float4 w; w.x=o[0]; w.y=o[1]; w.z=o[2]; w.w=o[3];
  *reinterpret_cast<float4*>(&Z[i4*4]) = w;
}

// ---------------- final dot: out[b] = z3[b,:] . quant(W3) + b3 ----------------
__global__ __launch_bounds__(256) void k_final(const float* __restrict__ Z3,
                                               const float* __restrict__ W3,
                                               const float* __restrict__ b3,
                                               float* __restrict__ out)
{
  const int b = blockIdx.x;
  const int tid = threadIdx.x;
  float s = 0.f;
  for (int j = tid; j < 2048; j += 256)
    s += Z3[(size_t)b*2048 + j] * qw(W3[j]);
  __shared__ float red[256];
  red[tid] = s;
  __syncthreads();
  for (int off = 128; off > 0; off >>= 1) {
    if (tid < off) red[tid] += red[tid+off];
    __syncthreads();
  }
  if (tid == 0) out[b] = red[0] + b3[0];
}

extern "C" void kernel_launch(void* const* d_in, const int* in_sizes, int n_in,
                              void* d_out, int out_size, void* d_ws, size_t ws_size,
                              hipStream_t stream)
{
  const int*   x    = (const int*)d_in[0];
  const int*   gs   = (const int*)d_in[1];
  const float* emb  = (const float*)d_in[2];
  const float* cw   = (const float*)d_in[3];
  // d_in[4] conv_b: cancels through BN1 (per-channel shift) -> unused
  const float* bn1g = (const float*)d_in[5];
  const float* bn1b = (const float*)d_in[6];
  const float* bnpg = (const float*)d_in[7];
  const float* bnpb = (const float*)d_in[8];
  const float* W1   = (const float*)d_in[9];
  // d_in[10] b1: cancels through FC BN -> unused
  const float* g1   = (const float*)d_in[11];
  const float* be1  = (const float*)d_in[12];
  const float* W2   = (const float*)d_in[13];
  // d_in[14] b2: cancels -> unused
  const float* g2   = (const float*)d_in[15];
  const float* be2  = (const float*)d_in[16];
  const float* W3   = (const float*)d_in[17];
  const float* b3   = (const float*)d_in[18];
  float* ws  = (float*)d_ws;
  float* out = (float*)d_out;

  k_gtable<<<1280, 256, 0, stream>>>(emb, cw, ws + OFF_G);
  k_passA<<<dim3(31, BATCH), 256, 0, stream>>>(x, gs, ws + OFF_G, ws + OFF_PA);
  k_bnreduce<0><<<160, 256, 0, stream>>>(ws + OFF_PA, bn1g, bn1b, ws + OFF_BN1);
  k_passB<<<dim3(31, BATCH), 256, 0, stream>>>(x, gs, ws + OFF_G, ws + OFF_BN1,
                                               ws + OFF_Z, ws + OFF_PB);
  k_bnreduce<1><<<160, 256, 0, stream>>>(ws + OFF_PB, bnpg, bnpb, ws + OFF_BNP);
  k_znorm<<<30720, 256, 0, stream>>>(ws + OFF_Z, ws + OFF_BNP);

  k_gemm<1920><<<dim3(32, 32), 256, 0, stream>>>(ws + OFF_Z, W1, ws + OFF_Y, 2048);
  k_colpart<<<dim3(32, 16), 256, 0, stream>>>(ws + OFF_Y, (double*)(ws + OFF_CP), 2048);
  k_colfinal<<<8, 256, 0, stream>>>((const double*)(ws + OFF_CP), g1, be1, ws + OFF_BNF1, 2048);
  k_act<<<8192, 256, 0, stream>>>(ws + OFF_Y, ws + OFF_BNF1, ws + OFF_Z2);

  k_gemm<2048><<<dim3(32, 32), 256, 0, stream>>>(ws + OFF_Z2, W2, ws + OFF_Y, 2048);
  k_colpart<<<dim3(32, 16), 256, 0, stream>>>(ws + OFF_Y, (double*)(ws + OFF_CP), 2048);
  k_colfinal<<<8, 256, 0, stream>>>((const double*)(ws + OFF_CP), g2, be2, ws + OFF_BNF2, 2048);
  k_act<<<8192, 256, 0, stream>>>(ws + OFF_Y, ws + OFF_BNF2, ws + OFF_G);  // z3 reuses g region

  k_final<<<4096, 256, 0, stream>>>(ws + OFF_G, W3, b3, out);
}

// Round 2
// 1829.498 us; speedup vs baseline: 2.0874x; 2.0874x over previous
//
#include <hip/hip_runtime.h>
#include <cmath>

#define HTOT  590
#define BATCH 4096
#define VOCAB 8192

// ---------------- workspace layout (float units) ----------------
constexpr size_t SZ_G    = 5ull*VOCAB*224;        // 9,175,040  g-table
constexpr size_t OFF_G   = 0;
constexpr size_t SZ_P    = (size_t)BATCH*320;     // 1,310,720 per-b BN partials
constexpr size_t OFF_PA  = OFF_G  + SZ_G;
constexpr size_t OFF_PB  = OFF_PA + SZ_P;
constexpr size_t OFF_BN1 = OFF_PB + SZ_P;         // 320
constexpr size_t OFF_BNP = OFF_BN1 + 320;         // 320
constexpr size_t SZ_Z    = 4096ull*1920;
constexpr size_t OFF_Z   = OFF_BNP + 320;
constexpr size_t SZ_Y    = 4096ull*2048;
constexpr size_t OFF_Y   = OFF_Z  + SZ_Z;
constexpr size_t OFF_Z2  = OFF_Y  + SZ_Y;
constexpr size_t OFF_CP  = OFF_Z2 + SZ_Y;         // 2048*32 doubles = 131072 floats
constexpr size_t OFF_BNF1= OFF_CP + 131072;
constexpr size_t OFF_BNF2= OFF_BNF1 + 4096;
// z3 reuses OFF_G (8,388,608 <= 9,175,040); g is rebuilt every call.

__device__ __forceinline__ float qw(float w) {
  return rintf(fminf(fmaxf(w, -1.f), 1.f));      // quant_signed(clip(w), 2)
}

// ---------------- g-table: g[slice][v][k*32+f] = sum_c emb[v][c]*w[f][c][k] ----------------
__global__ __launch_bounds__(256) void k_gtable(const float* __restrict__ emb,
                                                const float* __restrict__ convw,
                                                float* __restrict__ g)
{
  const int slice = blockIdx.x >> 8;           // 5 slices x 256 vblocks
  const int v0 = (blockIdx.x & 255) * 32;
  const int tid = threadIdx.x;
  __shared__ float wsb[32*225];                // padded: f*225 + c*7 + k
  __shared__ float eb[32];
  const float* wsl = convw + slice*(32*32*7);
  for (int j = tid; j < 32*224; j += 256) {
    const int f = j / 224, r = j - f*224;
    wsb[f*225 + r] = wsl[j];
  }
  const float* esl = emb + (size_t)slice*VOCAB*32;
  float* gsl = g + (size_t)slice*VOCAB*224;
  const int k = tid >> 5, f = tid & 31;
  for (int vi = 0; vi < 32; ++vi) {
    __syncthreads();
    if (tid < 32) eb[tid] = esl[(size_t)(v0+vi)*32 + tid];
    __syncthreads();
    if (tid < 224) {
      float acc = 0.f;
      #pragma unroll 8
      for (int c = 0; c < 32; ++c) acc += eb[c] * wsb[f*225 + c*7 + k];
      gsl[(size_t)(v0+vi)*224 + tid] = acc;
    }
  }
}

// ---------------- conv passes: direct g-loads, one block per batch element ----------------
// PASS 0: accumulate per-(slice,f) sum(h), sum(h^2) partials for BN1.
// PASS 1: conv + BN1 + tanh + avgpool -> z, plus per-(slice,f) pooled partials.
template<int PASS>
__global__ __launch_bounds__(256) void k_conv(const int* __restrict__ x,
                                              const int* __restrict__ gshift,
                                              const float* __restrict__ g,
                                              const float* __restrict__ bn1,
                                              float* __restrict__ z,
                                              float* __restrict__ partials)
{
  const int b   = blockIdx.x;
  const int tid = threadIdx.x;
  __shared__ int   toks[640];                   // [39+i] = x[b][i]; [0..38] = wrap tail
  __shared__ int   sOff[5];
  __shared__ float part[PASS == 0 ? 3840 : 1920];

  for (int i = tid; i < 629; i += 256) {
    int src = i - 39; if (src < 0) src += HTOT;
    toks[i] = x[b*HTOT + src];
  }
  if (tid == 0) {
    const int gs = gshift[b];
    sOff[0] = 548 + 39;                         // 590-42
    sOff[1] = 512 + 39;                         // 590-78
    sOff[2] = 440 - gs % 12 + 39;               // 590-150-s
    sOff[3] = 296 - gs % 24 + 39;               // 590-294-s
    sOff[4] = 8   - gs % 48 + 39;               // 590-582-s  (>= 0 after +39)
  }
  __syncthreads();

  for (int idx = tid; idx < 1920; idx += 256) {
    const int slice = idx / 384;
    const int o  = idx - slice*384;
    const int tp = o >> 5, f = o & 31;
    int pw;
    switch (slice) { case 0: pw=3; break; case 1: pw=6; break; case 2: pw=12; break;
                     case 3: pw=24; break; default: pw=48; }
    const float* __restrict__ gp = g + (size_t)slice*(VOCAB*224) + f;
    const int base = sOff[slice] + tp*pw;

    if (PASS == 0) {
      float s1 = 0.f, s2 = 0.f;
      for (int j = 0; j < pw; ++j) {
        const int q = base + j;
        const float h = gp[toks[q  ]*224      ]
                      + gp[toks[q+1]*224 +  32]
                      + gp[toks[q+2]*224 +  64]
                      + gp[toks[q+3]*224 +  96]
                      + gp[toks[q+4]*224 + 128]
                      + gp[toks[q+5]*224 + 160]
                      + gp[toks[q+6]*224 + 192];
        s1 += h; s2 += h*h;
      }
      part[idx]        = s1;
      part[1920 + idx] = s2;
    } else {
      const float A1 = bn1[(slice*32+f)*2];
      const float B1 = bn1[(slice*32+f)*2+1];
      float acc = 0.f;
      for (int j = 0; j < pw; ++j) {
        const int q = base + j;
        const float h = gp[toks[q  ]*224      ]
                      + gp[toks[q+1]*224 +  32]
                      + gp[toks[q+2]*224 +  64]
                      + gp[toks[q+3]*224 +  96]
                      + gp[toks[q+4]*224 + 128]
                      + gp[toks[q+5]*224 + 160]
                      + gp[toks[q+6]*224 + 192];
        const float u = A1*h + B1;
        const float e = __expf(2.f*u);
        acc += 1.f - __fdividef(2.f, e + 1.f);  // tanh(u)
      }
      const float pv = acc / (float)pw;
      z[(size_t)b*1920 + slice*384 + f*12 + tp] = pv;
      part[idx] = pv;
    }
  }
  __syncthreads();

  if (tid < 160) {
    const int slice = tid >> 5, f = tid & 31;
    const int base = slice*384 + f;
    float a = 0.f, c = 0.f;
    if (PASS == 0) {
      #pragma unroll
      for (int tp = 0; tp < 12; ++tp) {
        a += part[base + tp*32];
        c += part[1920 + base + tp*32];
      }
    } else {
      #pragma unroll
      for (int tp = 0; tp < 12; ++tp) {
        const float v = part[base + tp*32];
        a += v; c += v*v;
      }
    }
    float* dst = partials + (size_t)b*320 + tid*2;
    dst[0] = a; dst[1] = c;
  }
}

// ---------------- final BN stat reduce: per-b partials -> {A=g*rstd, B=beta-A*m} ----------------
template<int PASS>
__global__ __launch_bounds__(256) void k_bnfinal(const float* __restrict__ partials,
                                                 const float* __restrict__ gamma,
                                                 const float* __restrict__ beta,
                                                 float* __restrict__ outAB)
{
  const int c = blockIdx.x;                     // 0..159  (slice*32+f)
  const int tid = threadIdx.x;
  double s1 = 0.0, s2 = 0.0;
  for (int b = tid; b < BATCH; b += 256) {
    const float* p = partials + (size_t)b*320 + c*2;
    s1 += (double)p[0]; s2 += (double)p[1];
  }
  __shared__ double r1[256], r2[256];
  r1[tid] = s1; r2[tid] = s2;
  __syncthreads();
  for (int off = 128; off > 0; off >>= 1) {
    if (tid < off) { r1[tid] += r1[tid+off]; r2[tid] += r2[tid+off]; }
    __syncthreads();
  }
  if (tid == 0) {
    const int slice = c >> 5;
    long N;
    if (PASS == 0) { const long Tall[5] = {36,72,144,288,576}; N = (long)BATCH * Tall[slice]; }
    else           { N = (long)BATCH * 12; }
    const double m   = r1[0]/(double)N;
    const double var = r2[0]/(double)N - m*m;
    const float rstd = (float)(1.0/sqrt(var + 1e-5));
    const float Aa = gamma[c]*rstd;
    const float Bb = beta[c] - Aa*(float)m;
    outAB[c*2]   = Aa;
    outAB[c*2+1] = Bb;
  }
}

// ---------------- apply pooled BN to features (in place) ----------------
__global__ __launch_bounds__(256) void k_znorm(float* __restrict__ z,
                                               const float* __restrict__ bnp)
{
  const size_t i = (size_t)blockIdx.x*256 + threadIdx.x;   // exactly 4096*1920
  const int j = (int)(i % 1920);
  const int slice = j / 384;
  const int f = (j - slice*384) / 12;
  const float Aa = bnp[(slice*32+f)*2];
  const float Bb = bnp[(slice*32+f)*2+1];
  z[i] = z[i]*Aa + Bb;
}

// ---------------- fp32 tiled GEMM: C[4096,N] = A[4096,KD] * quant(W[N,KD])^T ----------------
template<int KD>
__global__ __launch_bounds__(256) void k_gemm(const float* __restrict__ A,
                                              const float* __restrict__ W,
                                              float* __restrict__ C, int N)
{
  const int bm = blockIdx.y * 128;
  const int bn = blockIdx.x * 64;
  const int tid = threadIdx.x;
  const int tx = tid & 15, ty = tid >> 4;
  __shared__ float As[16][132];
  __shared__ float Bs[16][68];
  float acc[8][4] = {};
  for (int k0 = 0; k0 < KD; k0 += 16) {
    #pragma unroll
    for (int u = 0; u < 2; ++u) {
      const int id = tid*2 + u;
      const int row = id >> 2, c4 = (id & 3)*4;
      const float4 v = *reinterpret_cast<const float4*>(&A[(size_t)(bm+row)*KD + k0 + c4]);
      As[c4+0][row]=v.x; As[c4+1][row]=v.y; As[c4+2][row]=v.z; As[c4+3][row]=v.w;
    }
    {
      const int row = tid >> 2, c4 = (tid & 3)*4;
      const float4 v = *reinterpret_cast<const float4*>(&W[(size_t)(bn+row)*KD + k0 + c4]);
      Bs[c4+0][row]=qw(v.x); Bs[c4+1][row]=qw(v.y); Bs[c4+2][row]=qw(v.z); Bs[c4+3][row]=qw(v.w);
    }
    __syncthreads();
    #pragma unroll
    for (int kk = 0; kk < 16; ++kk) {
      const float4 a0 = *reinterpret_cast<const float4*>(&As[kk][ty*8]);
      const float4 a1 = *reinterpret_cast<const float4*>(&As[kk][ty*8+4]);
      const float4 bv = *reinterpret_cast<const float4*>(&Bs[kk][tx*4]);
      const float av[8] = {a0.x,a0.y,a0.z,a0.w,a1.x,a1.y,a1.z,a1.w};
      const float bb[4] = {bv.x,bv.y,bv.z,bv.w};
      #pragma unroll
      for (int i = 0; i < 8; ++i)
        #pragma unroll
        for (int j = 0; j < 4; ++j)
          acc[i][j] = fmaf(av[i], bb[j], acc[i][j]);
    }
    __syncthreads();
  }
  #pragma unroll
  for (int i = 0; i < 8; ++i) {
    float4 o; o.x=acc[i][0]; o.y=acc[i][1]; o.z=acc[i][2]; o.w=acc[i][3];
    *reinterpret_cast<float4*>(&C[(size_t)(bm+ty*8+i)*N + bn + tx*4]) = o;
  }
}

// ---------------- column stats (2-stage, deterministic) ----------------
__global__ __launch_bounds__(256) void k_colpart(const float* __restrict__ Y,
                                                 double* __restrict__ part, int N)
{
  const int c0 = blockIdx.x*64;
  const int chunk = blockIdx.y;        // 16 chunks of 256 rows
  const int tid = threadIdx.x;
  const int c = tid & 63, rq = tid >> 6;
  double s1 = 0.0, s2 = 0.0;
  const int rbase = chunk*256;
  for (int r = rbase + rq; r < rbase+256; r += 4) {
    const float v = Y[(size_t)r*N + c0 + c];
    s1 += (double)v; s2 += (double)v*(double)v;
  }
  __shared__ double r1[256], r2[256];
  r1[tid] = s1; r2[tid] = s2;
  __syncthreads();
  if (tid < 64) {
    const double a  = r1[tid]+r1[tid+64]+r1[tid+128]+r1[tid+192];
    const double cc = r2[tid]+r2[tid+64]+r2[tid+128]+r2[tid+192];
    part[(size_t)(c0+c)*32 + chunk*2]     = a;
    part[(size_t)(c0+c)*32 + chunk*2 + 1] = cc;
  }
}

__global__ __launch_bounds__(256) void k_colfinal(const double* __restrict__ part,
                                                  const float* __restrict__ gamma,
                                                  const float* __restrict__ beta,
                                                  float* __restrict__ bnfc, int N)
{
  const int c = blockIdx.x*256 + threadIdx.x;
  if (c >= N) return;
  double s1 = 0.0, s2 = 0.0;
  #pragma unroll
  for (int ch = 0; ch < 16; ++ch) {
    s1 += part[(size_t)c*32 + ch*2];
    s2 += part[(size_t)c*32 + ch*2 + 1];
  }
  const double m   = s1/4096.0;
  const double var = s2/4096.0 - m*m;
  const float rstd = (float)(1.0/sqrt(var + 1e-5));
  const float Aa = gamma[c]*rstd;
  const float Bb = beta[c] - Aa*(float)m;
  bnfc[c*2] = Aa; bnfc[c*2+1] = Bb;
}

// ---------------- BN + hardtanh + 3-bit quantize ----------------
__global__ __launch_bounds__(256) void k_act(const float* __restrict__ Y,
                                             const float* __restrict__ bnfc,
                                             float* __restrict__ Z)
{
  const size_t i4 = (size_t)blockIdx.x*256 + threadIdx.x;  // exactly 2,097,152 float4s
  const int cbase = (int)((i4*4) & 2047);
  const float4 v = *reinterpret_cast<const float4*>(&Y[i4*4]);
  float o[4] = {v.x, v.y, v.z, v.w};
  #pragma unroll
  for (int j = 0; j < 4; ++j) {
    const float Aa = bnfc[(cbase+j)*2], Bb = bnfc[(cbase+j)*2+1];
    float t = o[j]*Aa + Bb;
    t = fminf(fmaxf(t, -1.f), 1.f);
    o[j] = rintf(t*3.f)/3.f;
  }
  float4 w; w.x=o[0]; w.y=o[1]; w.z=o[2]; w.w=o[3];
  *reinterpret_cast<float4*>(&Z[i4*4]) = w;
}

// ---------------- final dot: out[b] = z3[b,:] . quant(W3) + b3 ----------------
__global__ __launch_bounds__(256) void k_final(const float* __restrict__ Z3,
                                               const float* __restrict__ W3,
                                               const float* __restrict__ b3,
                                               float* __restrict__ out)
{
  const int b = blockIdx.x;
  const int tid = threadIdx.x;
  float s = 0.f;
  for (int j = tid; j < 2048; j += 256)
    s += Z3[(size_t)b*2048 + j] * qw(W3[j]);
  __shared__ float red[256];
  red[tid] = s;
  __syncthreads();
  for (int off = 128; off > 0; off >>= 1) {
    if (tid < off) red[tid] += red[tid+off];
    __syncthreads();
  }
  if (tid == 0) out[b] = red[0] + b3[0];
}

extern "C" void kernel_launch(void* const* d_in, const int* in_sizes, int n_in,
                              void* d_out, int out_size, void* d_ws, size_t ws_size,
                              hipStream_t stream)
{
  const int*   x    = (const int*)d_in[0];
  const int*   gs   = (const int*)d_in[1];
  const float* emb  = (const float*)d_in[2];
  const float* cw   = (const float*)d_in[3];
  // d_in[4] conv_b: cancels through BN1 (per-channel shift) -> unused
  const float* bn1g = (const float*)d_in[5];
  const float* bn1b = (const float*)d_in[6];
  const float* bnpg = (const float*)d_in[7];
  const float* bnpb = (const float*)d_in[8];
  const float* W1   = (const float*)d_in[9];
  // d_in[10] b1: cancels through FC BN -> unused
  const float* g1   = (const float*)d_in[11];
  const float* be1  = (const float*)d_in[12];
  const float* W2   = (const float*)d_in[13];
  // d_in[14] b2: cancels -> unused
  const float* g2   = (const float*)d_in[15];
  const float* be2  = (const float*)d_in[16];
  const float* W3   = (const float*)d_in[17];
  const float* b3   = (const float*)d_in[18];
  float* ws  = (float*)d_ws;
  float* out = (float*)d_out;

  k_gtable<<<1280, 256, 0, stream>>>(emb, cw, ws + OFF_G);
  k_conv<0><<<BATCH, 256, 0, stream>>>(x, gs, ws + OFF_G, nullptr, nullptr, ws + OFF_PA);
  k_bnfinal<0><<<160, 256, 0, stream>>>(ws + OFF_PA, bn1g, bn1b, ws + OFF_BN1);
  k_conv<1><<<BATCH, 256, 0, stream>>>(x, gs, ws + OFF_G, ws + OFF_BN1,
                                       ws + OFF_Z, ws + OFF_PB);
  k_bnfinal<1><<<160, 256, 0, stream>>>(ws + OFF_PB, bnpg, bnpb, ws + OFF_BNP);
  k_znorm<<<30720, 256, 0, stream>>>(ws + OFF_Z, ws + OFF_BNP);

  k_gemm<1920><<<dim3(32, 32), 256, 0, stream>>>(ws + OFF_Z, W1, ws + OFF_Y, 2048);
  k_colpart<<<dim3(32, 16), 256, 0, stream>>>(ws + OFF_Y, (double*)(ws + OFF_CP), 2048);
  k_colfinal<<<8, 256, 0, stream>>>((const double*)(ws + OFF_CP), g1, be1, ws + OFF_BNF1, 2048);
  k_act<<<8192, 256, 0, stream>>>(ws + OFF_Y, ws + OFF_BNF1, ws + OFF_Z2);

  k_gemm<2048><<<dim3(32, 32), 256, 0, stream>>>(ws + OFF_Z2, W2, ws + OFF_Y, 2048);
  k_colpart<<<dim3(32, 16), 256, 0, stream>>>(ws + OFF_Y, (double*)(ws + OFF_CP), 2048);
  k_colfinal<<<8, 256, 0, stream>>>((const double*)(ws + OFF_CP), g2, be2, ws + OFF_BNF2, 2048);
  k_act<<<8192, 256, 0, stream>>>(ws + OFF_Y, ws + OFF_BNF2, ws + OFF_G);  // z3 reuses g region

  k_final<<<4096, 256, 0, stream>>>(ws + OFF_G, W3, b3, out);
}

// Round 3
// 1169.279 us; speedup vs baseline: 3.2661x; 1.5646x over previous
//
#include <hip/hip_runtime.h>
#include <cmath>

#define HTOT  590
#define BATCH 4096
#define VOCAB 8192

typedef _Float16 f16;
typedef __attribute__((ext_vector_type(8))) _Float16 f16x8;
typedef __attribute__((ext_vector_type(4))) _Float16 f16x4;
typedef __attribute__((ext_vector_type(4))) float f32x4;

// ---------------- workspace layout (float units) ----------------
// R0: g-table fp32 (conv) -> zhi/zlo f16 (GEMM1 A) -> z2k f16 (GEMM2 A) + z3k f16
constexpr size_t OFF_G    = 0;                     // 9,175,040 floats (36.7MB)
constexpr size_t OFF_ZH   = 0;                     // 7,864,320 f16 = 3,932,160 fl
constexpr size_t OFF_ZL   = 3932160;
constexpr size_t OFF_Z2K  = 0;                     // 8,388,608 f16 = 4,194,304 fl
constexpr size_t OFF_Z3K  = 4194304;               // ends 8,388,608 <= 9,175,040
constexpr size_t OFF_PA   = 9175040;               // 1,310,720
constexpr size_t OFF_PB   = 10485760;              // 1,310,720
constexpr size_t OFF_BN1  = 11796480;              // 320 (SoA: [0,160)=A, [160,320)=B)
constexpr size_t OFF_BNP  = 11796800;              // 320
constexpr size_t OFF_CP   = 11797120;              // 131,072 (2048*16*2 doubles)
constexpr size_t OFF_BNF1 = 11928192;              // 4,096 (SoA: [0,2048)=A,[2048,4096)=B)
constexpr size_t OFF_BNF2 = 11932288;              // 4,096
// R2: p_raw fp32 (conv out) -> W1p/W2p f16 (GEMM B)
constexpr size_t OFF_PRAW = 11936384;              // 7,864,320
constexpr size_t OFF_W1P  = 11936384;              // 3,932,160 f16 = 1,966,080 fl
constexpr size_t OFF_W2P  = 13902464;              // 4,194,304 f16 = 2,097,152 fl
constexpr size_t OFF_Y    = 19800704;              // 8,388,608
constexpr size_t OFF_H    = 28189312;              // optional h fp32: 4096*1116*32
constexpr size_t END_NOH  = 28189312;              // 112.8 MB (proven fits)
constexpr size_t END_H    = 174465664;             // 697.9 MB (runtime-checked)

__device__ __forceinline__ float qw(float w) {
  return rintf(fminf(fmaxf(w, -1.f), 1.f));        // quant_signed(clip(w), 2)
}
__device__ __forceinline__ float4 ld4(const float* p) {
  return *reinterpret_cast<const float4*>(p);
}
__device__ __forceinline__ float tanh_c(float u) {
  const float e = __expf(2.f*u);
  return 1.f - __fdividef(2.f, e + 1.f);
}

// ---------------- g-table: g[slice][v][k*32+f] = sum_c emb[v][c]*w[f][c][k] ----------------
__global__ __launch_bounds__(256) void k_gtable(const float* __restrict__ emb,
                                                const float* __restrict__ convw,
                                                float* __restrict__ g)
{
  const int slice = blockIdx.x >> 8;
  const int v0 = (blockIdx.x & 255) * 32;
  const int tid = threadIdx.x;
  __shared__ float wsb[32*225];                    // f*225 + c*7 + k
  __shared__ float eb[32];
  const float* wsl = convw + slice*(32*32*7);
  for (int j = tid; j < 32*224; j += 256) {
    const int f = j / 224, r = j - f*224;
    wsb[f*225 + r] = wsl[j];
  }
  const float* esl = emb + (size_t)slice*VOCAB*32;
  float* gsl = g + (size_t)slice*VOCAB*224;
  const int k = tid >> 5, f = tid & 31;
  for (int vi = 0; vi < 32; ++vi) {
    __syncthreads();
    if (tid < 32) eb[tid] = esl[(size_t)(v0+vi)*32 + tid];
    __syncthreads();
    if (tid < 224) {
      float acc = 0.f;
      #pragma unroll 8
      for (int c = 0; c < 32; ++c) acc += eb[c] * wsb[f*225 + c*7 + k];
      gsl[(size_t)(v0+vi)*224 + tid] = acc;
    }
  }
}

// ---------------- conv pass A: stats (+ optional h store), float4 gather ----------------
template<int STOREH>
__global__ __launch_bounds__(256) void k_convA(const int* __restrict__ x,
                                               const int* __restrict__ gshift,
                                               const float* __restrict__ g,
                                               float* __restrict__ partials,
                                               float* __restrict__ hbuf)
{
  const int b = blockIdx.x, tid = threadIdx.x;
  __shared__ int   toks[640];                      // pre-scaled: tok*224
  __shared__ int   sOff[8];
  __shared__ float part[3840];
  for (int i = tid; i < 629; i += 256) {
    int src = i - 39; if (src < 0) src += HTOT;
    toks[i] = x[b*HTOT + src] * 224;
  }
  if (tid == 0) {
    const int gs = gshift[b];
    sOff[0] = 548 + 39; sOff[1] = 512 + 39;
    sOff[2] = 440 - gs % 12 + 39;
    sOff[3] = 296 - gs % 24 + 39;
    sOff[4] = 8   - gs % 48 + 39;
  }
  __syncthreads();
  const int PWs[5]  = {3,6,12,24,48};
  const int SPos[5] = {0,36,108,252,540};
  for (int idx = tid; idx < 480; idx += 256) {
    const int slice = idx / 96;
    const int r = idx - slice*96;
    const int tp = r >> 3, f4 = r & 7;
    const int pw = PWs[slice];
    const float* __restrict__ gp4 = g + (size_t)slice*(VOCAB*224) + f4*4;
    const int base = sOff[slice] + tp*pw;
    float* __restrict__ hdst = hbuf + (size_t)b*35712 + (size_t)(SPos[slice] + tp*pw)*32 + f4*4;
    float4 s1 = {0,0,0,0}, s2 = {0,0,0,0};
    for (int j = 0; j < pw; ++j) {
      float4 h = ld4(gp4 + toks[base+j]);
      #pragma unroll
      for (int k = 1; k < 7; ++k) {
        const float4 v = ld4(gp4 + toks[base+j+k] + k*32);
        h.x += v.x; h.y += v.y; h.z += v.z; h.w += v.w;
      }
      if (STOREH) *reinterpret_cast<float4*>(hdst + j*32) = h;
      s1.x += h.x; s1.y += h.y; s1.z += h.z; s1.w += h.w;
      s2.x += h.x*h.x; s2.y += h.y*h.y; s2.z += h.z*h.z; s2.w += h.w*h.w;
    }
    *reinterpret_cast<float4*>(&part[idx*4])        = s1;
    *reinterpret_cast<float4*>(&part[1920 + idx*4]) = s2;
  }
  __syncthreads();
  if (tid < 160) {
    const int slice = tid >> 5, f = tid & 31;
    float a = 0.f, c = 0.f;
    #pragma unroll
    for (int tp = 0; tp < 12; ++tp) {
      const int q = (slice*96 + tp*8 + (f>>2))*4 + (f&3);
      a += part[q]; c += part[1920 + q];
    }
    float* dst = partials + (size_t)b*320 + tid*2;
    dst[0] = a; dst[1] = c;
  }
}

// ---------------- conv pass B: conv(+read h) + BN1 + tanh + avgpool ----------------
template<int READH>
__global__ __launch_bounds__(256) void k_convB(const int* __restrict__ x,
                                               const int* __restrict__ gshift,
                                               const float* __restrict__ g,
                                               const float* __restrict__ hbuf,
                                               const float* __restrict__ bn1,  // SoA A/B
                                               float* __restrict__ z,
                                               float* __restrict__ partials)
{
  const int b = blockIdx.x, tid = threadIdx.x;
  __shared__ int   toks[640];
  __shared__ int   sOff[8];
  __shared__ float part[1920];
  if (!READH) {
    for (int i = tid; i < 629; i += 256) {
      int src = i - 39; if (src < 0) src += HTOT;
      toks[i] = x[b*HTOT + src] * 224;
    }
    if (tid == 0) {
      const int gs = gshift[b];
      sOff[0] = 548 + 39; sOff[1] = 512 + 39;
      sOff[2] = 440 - gs % 12 + 39;
      sOff[3] = 296 - gs % 24 + 39;
      sOff[4] = 8   - gs % 48 + 39;
    }
    __syncthreads();
  }
  const int PWs[5]  = {3,6,12,24,48};
  const int SPos[5] = {0,36,108,252,540};
  for (int idx = tid; idx < 480; idx += 256) {
    const int slice = idx / 96;
    const int r = idx - slice*96;
    const int tp = r >> 3, f4 = r & 7;
    const int pw = PWs[slice];
    const float4 A1 = ld4(bn1 + slice*32 + f4*4);
    const float4 B1 = ld4(bn1 + 160 + slice*32 + f4*4);
    const float* __restrict__ gp4 = g + (size_t)slice*(VOCAB*224) + f4*4;
    const float* __restrict__ hsrc = hbuf + (size_t)b*35712 + (size_t)(SPos[slice] + tp*pw)*32 + f4*4;
    const int base = READH ? 0 : (sOff[slice] + tp*pw);
    float4 acc = {0,0,0,0};
    for (int j = 0; j < pw; ++j) {
      float4 h;
      if (READH) {
        h = ld4(hsrc + j*32);
      } else {
        h = ld4(gp4 + toks[base+j]);
        #pragma unroll
        for (int k = 1; k < 7; ++k) {
          const float4 v = ld4(gp4 + toks[base+j+k] + k*32);
          h.x += v.x; h.y += v.y; h.z += v.z; h.w += v.w;
        }
      }
      acc.x += tanh_c(A1.x*h.x + B1.x);
      acc.y += tanh_c(A1.y*h.y + B1.y);
      acc.z += tanh_c(A1.z*h.z + B1.z);
      acc.w += tanh_c(A1.w*h.w + B1.w);
    }
    const float fpw = (float)pw;
    float4 pv; pv.x = acc.x/fpw; pv.y = acc.y/fpw; pv.z = acc.z/fpw; pv.w = acc.w/fpw;
    // z layout: [b][slice*384 + tp*32 + f]  (GEMM1 K-order; W1 pre-permuted to match)
    *reinterpret_cast<float4*>(&z[(size_t)b*1920 + slice*384 + tp*32 + f4*4]) = pv;
    *reinterpret_cast<float4*>(&part[idx*4]) = pv;
  }
  __syncthreads();
  if (tid < 160) {
    const int slice = tid >> 5, f = tid & 31;
    float a = 0.f, c = 0.f;
    #pragma unroll
    for (int tp = 0; tp < 12; ++tp) {
      const float v = part[(slice*96 + tp*8 + (f>>2))*4 + (f&3)];
      a += v; c += v*v;
    }
    float* dst = partials + (size_t)b*320 + tid*2;
    dst[0] = a; dst[1] = c;
  }
}

// ---------------- BN stat reduce -> SoA {A=g*rstd, B=beta-A*m} ----------------
template<int PASS>
__global__ __launch_bounds__(256) void k_bnfinal(const float* __restrict__ partials,
                                                 const float* __restrict__ gamma,
                                                 const float* __restrict__ beta,
                                                 float* __restrict__ outAB)
{
  const int c = blockIdx.x;                        // 0..159
  const int tid = threadIdx.x;
  double s1 = 0.0, s2 = 0.0;
  for (int b = tid; b < BATCH; b += 256) {
    const float* p = partials + (size_t)b*320 + c*2;
    s1 += (double)p[0]; s2 += (double)p[1];
  }
  __shared__ double r1[256], r2[256];
  r1[tid] = s1; r2[tid] = s2;
  __syncthreads();
  for (int off = 128; off > 0; off >>= 1) {
    if (tid < off) { r1[tid] += r1[tid+off]; r2[tid] += r2[tid+off]; }
    __syncthreads();
  }
  if (tid == 0) {
    const int slice = c >> 5;
    long N;
    if (PASS == 0) { const long Tall[5] = {36,72,144,288,576}; N = (long)BATCH * Tall[slice]; }
    else           { N = (long)BATCH * 12; }
    const double m   = r1[0]/(double)N;
    const double var = r2[0]/(double)N - m*m;
    const float rstd = (float)(1.0/sqrt(var + 1e-5));
    const float Aa = gamma[c]*rstd;
    outAB[c]       = Aa;
    outAB[160 + c] = beta[c] - Aa*(float)m;
  }
}

// ---------------- pooled BN apply + f16 hi/lo split: praw -> zhi, zlo ----------------
__global__ __launch_bounds__(256) void k_znorm(const float* __restrict__ praw,
                                               const float* __restrict__ bnp,
                                               f16* __restrict__ zhi,
                                               f16* __restrict__ zlo)
{
  const size_t i4 = (size_t)blockIdx.x*256 + threadIdx.x;  // exactly 1,966,080
  const float4 v = ld4(praw + i4*4);
  const int j = (int)((i4*4) % 1920);
  const int slice = j / 384, f0 = j & 31;
  const float4 A = ld4(bnp + slice*32 + f0);
  const float4 B = ld4(bnp + 160 + slice*32 + f0);
  const float zn[4] = {v.x*A.x+B.x, v.y*A.y+B.y, v.z*A.z+B.z, v.w*A.w+B.w};
  f16x4 hv, lv;
  #pragma unroll
  for (int e = 0; e < 4; ++e) {
    const f16 h = (f16)zn[e];
    hv[e] = h;
    lv[e] = (f16)(zn[e] - (float)h);
  }
  *reinterpret_cast<f16x4*>(&zhi[i4*4]) = hv;
  *reinterpret_cast<f16x4*>(&zlo[i4*4]) = lv;
}

// ---------------- weight prep: quantize (+permute for W1) to f16 ----------------
__global__ __launch_bounds__(256) void k_wprep1(const float* __restrict__ W1,
                                                f16* __restrict__ W1p)
{
  const int idx = blockIdx.x*256 + threadIdx.x;    // < 3,932,160
  const int n = idx / 1920, klds = idx - n*1920;
  const int slice = klds / 384, r = klds - slice*384;
  const int tp = r >> 5, f = r & 31;
  W1p[idx] = (f16)qw(W1[n*1920 + slice*384 + f*12 + tp]);
}

__global__ __launch_bounds__(256) void k_wprep2(const float* __restrict__ W2,
                                                f16* __restrict__ W2p)
{
  const size_t i4 = (size_t)blockIdx.x*256 + threadIdx.x;  // < 1,048,576
  const float4 v = ld4(W2 + i4*4);
  f16x4 o;
  o[0] = (f16)qw(v.x); o[1] = (f16)qw(v.y); o[2] = (f16)qw(v.z); o[3] = (f16)qw(v.w);
  *reinterpret_cast<f16x4*>(&W2p[i4*4]) = o;
}

// ---------------- MFMA GEMM: C[4096,2048] = A(hi+lo) @ Bp^T, f16 inputs fp32 accum ----------------
template<int SPLIT>
__global__ __launch_bounds__(256) void k_mfgemm(const f16* __restrict__ Ahi,
                                               const f16* __restrict__ Alo,
                                               const f16* __restrict__ Bp,
                                               float* __restrict__ C,
                                               const int K, const float oscale)
{
  __shared__ f16 sA[(SPLIT+1)*128][40];
  __shared__ f16 sB[128][40];
  const int tid = threadIdx.x;
  const int bm = blockIdx.y*128, bn = blockIdx.x*128;
  const int wid = tid >> 6, lane = tid & 63;
  const int wm = (wid >> 1)*64, wn = (wid & 1)*64;
  const int lgrp = lane >> 4, lrow = lane & 15;
  f32x4 acc[4][4];
  #pragma unroll
  for (int m = 0; m < 4; ++m)
    #pragma unroll
    for (int n = 0; n < 4; ++n) acc[m][n] = (f32x4){0.f,0.f,0.f,0.f};

  const int srow = tid >> 2, sc = (tid & 3)*8;
  for (int k0 = 0; k0 < K; k0 += 32) {
    #pragma unroll
    for (int u = 0; u < 2; ++u) {
      const int row = srow + u*64;
      const uint4 va = *reinterpret_cast<const uint4*>(&Ahi[(size_t)(bm+row)*K + k0 + sc]);
      *reinterpret_cast<uint4*>(&sA[row][sc]) = va;
      if (SPLIT) {
        const uint4 vl = *reinterpret_cast<const uint4*>(&Alo[(size_t)(bm+row)*K + k0 + sc]);
        *reinterpret_cast<uint4*>(&sA[128+row][sc]) = vl;
      }
      const uint4 vb = *reinterpret_cast<const uint4*>(&Bp[(size_t)(bn+row)*K + k0 + sc]);
      *reinterpret_cast<uint4*>(&sB[row][sc]) = vb;
    }
    __syncthreads();
    f16x8 bf[4];
    #pragma unroll
    for (int n = 0; n < 4; ++n)
      bf[n] = *reinterpret_cast<const f16x8*>(&sB[wn + n*16 + lrow][lgrp*8]);
    #pragma unroll
    for (int m = 0; m < 4; ++m) {
      const f16x8 ah = *reinterpret_cast<const f16x8*>(&sA[wm + m*16 + lrow][lgrp*8]);
      #pragma unroll
      for (int n = 0; n < 4; ++n)
        acc[m][n] = __builtin_amdgcn_mfma_f32_16x16x32_f16(ah, bf[n], acc[m][n], 0, 0, 0);
      if (SPLIT) {
        const f16x8 al = *reinterpret_cast<const f16x8*>(&sA[128 + wm + m*16 + lrow][lgrp*8]);
        #pragma unroll
        for (int n = 0; n < 4; ++n)
          acc[m][n] = __builtin_amdgcn_mfma_f32_16x16x32_f16(al, bf[n], acc[m][n], 0, 0, 0);
      }
    }
    __syncthreads();
  }
  #pragma unroll
  for (int m = 0; m < 4; ++m)
    #pragma unroll
    for (int n = 0; n < 4; ++n) {
      const int col = bn + wn + n*16 + lrow;
      #pragma unroll
      for (int r = 0; r < 4; ++r)
        C[(size_t)(bm + wm + m*16 + lgrp*4 + r)*2048 + col] = acc[m][n][r]*oscale;
    }
}

// ---------------- column stats (2-stage, deterministic) ----------------
__global__ __launch_bounds__(256) void k_colpart(const float* __restrict__ Y,
                                                 double* __restrict__ part, int N)
{
  const int c0 = blockIdx.x*64;
  const int chunk = blockIdx.y;
  const int tid = threadIdx.x;
  const int c = tid & 63, rq = tid >> 6;
  double s1 = 0.0, s2 = 0.0;
  const int rbase = chunk*256;
  for (int r = rbase + rq; r < rbase+256; r += 4) {
    const float v = Y[(size_t)r*N + c0 + c];
    s1 += (double)v; s2 += (double)v*(double)v;
  }
  __shared__ double r1[256], r2[256];
  r1[tid] = s1; r2[tid] = s2;
  __syncthreads();
  if (tid < 64) {
    const double a  = r1[tid]+r1[tid+64]+r1[tid+128]+r1[tid+192];
    const double cc = r2[tid]+r2[tid+64]+r2[tid+128]+r2[tid+192];
    part[(size_t)(c0+c)*32 + chunk*2]     = a;
    part[(size_t)(c0+c)*32 + chunk*2 + 1] = cc;
  }
}

__global__ __launch_bounds__(256) void k_colfinal(const double* __restrict__ part,
                                                  const float* __restrict__ gamma,
                                                  const float* __restrict__ beta,
                                                  float* __restrict__ bnfc, int N)
{
  const int c = blockIdx.x*256 + threadIdx.x;
  if (c >= N) return;
  double s1 = 0.0, s2 = 0.0;
  #pragma unroll
  for (int ch = 0; ch < 16; ++ch) {
    s1 += part[(size_t)c*32 + ch*2];
    s2 += part[(size_t)c*32 + ch*2 + 1];
  }
  const double m   = s1/4096.0;
  const double var = s2/4096.0 - m*m;
  const float rstd = (float)(1.0/sqrt(var + 1e-5));
  const float Aa = gamma[c]*rstd;
  bnfc[c]        = Aa;
  bnfc[2048 + c] = beta[c] - Aa*(float)m;
}

// ---------------- BN + hardtanh + quantize -> integer k in f16 ----------------
__global__ __launch_bounds__(256) void k_act(const float* __restrict__ Y,
                                             const float* __restrict__ bnfc,
                                             f16* __restrict__ Zk)
{
  const size_t i4 = (size_t)blockIdx.x*256 + threadIdx.x;  // exactly 2,097,152
  const int cbase = (int)((i4*4) & 2047);
  const float4 v = ld4(Y + i4*4);
  const float4 A = ld4(bnfc + cbase);
  const float4 B = ld4(bnfc + 2048 + cbase);
  const float t[4] = {v.x*A.x+B.x, v.y*A.y+B.y, v.z*A.z+B.z, v.w*A.w+B.w};
  f16x4 o;
  #pragma unroll
  for (int e = 0; e < 4; ++e) {
    const float c = fminf(fmaxf(t[e], -1.f), 1.f);
    o[e] = (f16)rintf(c*3.f);                      // exact small int in f16
  }
  *reinterpret_cast<f16x4*>(&Zk[i4*4]) = o;
}

// ---------------- final dot: out[b] = (z3k . quant(W3))/3 + b3 ----------------
__global__ __launch_bounds__(256) void k_final(const f16* __restrict__ Z3,
                                               const float* __restrict__ W3,
                                               const float* __restrict__ b3,
                                               float* __restrict__ out)
{
  const int b = blockIdx.x;
  const int tid = threadIdx.x;
  float s = 0.f;
  for (int j = tid; j < 2048; j += 256)
    s += (float)Z3[(size_t)b*2048 + j] * qw(W3[j]);
  __shared__ float red[256];
  red[tid] = s;
  __syncthreads();
  for (int off = 128; off > 0; off >>= 1) {
    if (tid < off) red[tid] += red[tid+off];
    __syncthreads();
  }
  if (tid == 0) out[b] = red[0]*(1.f/3.f) + b3[0];
}

extern "C" void kernel_launch(void* const* d_in, const int* in_sizes, int n_in,
                              void* d_out, int out_size, void* d_ws, size_t ws_size,
                              hipStream_t stream)
{
  const int*   x    = (const int*)d_in[0];
  const int*   gs   = (const int*)d_in[1];
  const float* emb  = (const float*)d_in[2];
  const float* cw   = (const float*)d_in[3];
  const float* bn1g = (const float*)d_in[5];
  const float* bn1b = (const float*)d_in[6];
  const float* bnpg = (const float*)d_in[7];
  const float* bnpb = (const float*)d_in[8];
  const float* W1   = (const float*)d_in[9];
  const float* g1   = (const float*)d_in[11];
  const float* be1  = (const float*)d_in[12];
  const float* W2   = (const float*)d_in[13];
  const float* g2   = (const float*)d_in[15];
  const float* be2  = (const float*)d_in[16];
  const float* W3   = (const float*)d_in[17];
  const float* b3   = (const float*)d_in[18];
  float* ws  = (float*)d_ws;
  float* out = (float*)d_out;

  const bool useH = ws_size >= (size_t)END_H * 4ull;
  float* hbuf = useH ? (ws + OFF_H) : ws;          // dummy when unused

  k_gtable<<<1280, 256, 0, stream>>>(emb, cw, ws + OFF_G);
  if (useH) k_convA<1><<<BATCH, 256, 0, stream>>>(x, gs, ws + OFF_G, ws + OFF_PA, hbuf);
  else      k_convA<0><<<BATCH, 256, 0, stream>>>(x, gs, ws + OFF_G, ws + OFF_PA, hbuf);
  k_bnfinal<0><<<160, 256, 0, stream>>>(ws + OFF_PA, bn1g, bn1b, ws + OFF_BN1);
  if (useH) k_convB<1><<<BATCH, 256, 0, stream>>>(x, gs, ws + OFF_G, hbuf, ws + OFF_BN1,
                                                  ws + OFF_PRAW, ws + OFF_PB);
  else      k_convB<0><<<BATCH, 256, 0, stream>>>(x, gs, ws + OFF_G, hbuf, ws + OFF_BN1,
                                                  ws + OFF_PRAW, ws + OFF_PB);
  k_bnfinal<1><<<160, 256, 0, stream>>>(ws + OFF_PB, bnpg, bnpb, ws + OFF_BNP);
  k_znorm<<<7680, 256, 0, stream>>>(ws + OFF_PRAW, ws + OFF_BNP,
                                    (f16*)(ws + OFF_ZH), (f16*)(ws + OFF_ZL));
  k_wprep1<<<15360, 256, 0, stream>>>(W1, (f16*)(ws + OFF_W1P));
  k_wprep2<<<4096, 256, 0, stream>>>(W2, (f16*)(ws + OFF_W2P));

  k_mfgemm<1><<<dim3(16, 32), 256, 0, stream>>>((const f16*)(ws + OFF_ZH),
                                                (const f16*)(ws + OFF_ZL),
                                                (const f16*)(ws + OFF_W1P),
                                                ws + OFF_Y, 1920, 1.f);
  k_colpart<<<dim3(32, 16), 256, 0, stream>>>(ws + OFF_Y, (double*)(ws + OFF_CP), 2048);
  k_colfinal<<<8, 256, 0, stream>>>((const double*)(ws + OFF_CP), g1, be1, ws + OFF_BNF1, 2048);
  k_act<<<8192, 256, 0, stream>>>(ws + OFF_Y, ws + OFF_BNF1, (f16*)(ws + OFF_Z2K));

  k_mfgemm<0><<<dim3(16, 32), 256, 0, stream>>>((const f16*)(ws + OFF_Z2K), nullptr,
                                                (const f16*)(ws + OFF_W2P),
                                                ws + OFF_Y, 2048, 1.f/3.f);
  k_colpart<<<dim3(32, 16), 256, 0, stream>>>(ws + OFF_Y, (double*)(ws + OFF_CP), 2048);
  k_colfinal<<<8, 256, 0, stream>>>((const double*)(ws + OFF_CP), g2, be2, ws + OFF_BNF2, 2048);
  k_act<<<8192, 256, 0, stream>>>(ws + OFF_Y, ws + OFF_BNF2, (f16*)(ws + OFF_Z3K));

  k_final<<<4096, 256, 0, stream>>>((const f16*)(ws + OFF_Z3K), W3, b3, out);
}

// Round 5
// 908.147 us; speedup vs baseline: 4.2052x; 1.2875x over previous
//
#include <hip/hip_runtime.h>
#include <cmath>

#define HTOT  590
#define BATCH 4096
#define VOCAB 8192

typedef _Float16 f16;
typedef __attribute__((ext_vector_type(8))) _Float16 f16x8;
typedef __attribute__((ext_vector_type(4))) _Float16 f16x4;
typedef __attribute__((ext_vector_type(4))) float f32x4;
typedef __attribute__((ext_vector_type(16))) float f32x16;

// ---------------- workspace layout (float units) ----------------
constexpr size_t OFF_EHL  = 0;           // 1,310,720 fl: e hi/lo f16 [5][8192][64f16]
constexpr size_t OFF_WF   = 1310720;     // 35,840 fl: wfrag f16 [5][7][2][2][64][8]
constexpr size_t OFF_PA   = 1347584;     // 1,572,864: [b][192][2] pass-A stats
constexpr size_t OFF_PB   = 2921472;     // 1,572,864: [b][192][2] pooled stats
constexpr size_t OFF_BN1  = 4494336;     // 320 (SoA A[160], B[160])
constexpr size_t OFF_BNP  = 4494656;     // 320
constexpr size_t OFF_CP   = 4494976;     // 131,072 (2048*16*2 doubles)
constexpr size_t OFF_BNF1 = 4626048;     // 4,096
constexpr size_t OFF_PRAW = 4630528;     // 7,864,320: p fp32 -> packed {hi,lo} f16 in place
constexpr size_t OFF_W1P  = 12494848;    // 1,966,080 (f16)
constexpr size_t OFF_W2P  = 14460928;    // 2,097,152 (f16)
constexpr size_t OFF_Y    = 16558080;    // 8,388,608
constexpr size_t OFF_BNF2 = 24946688;    // 4,096
constexpr size_t OFF_Z2K  = 0;           // conv-region dead by then
constexpr size_t OFF_Z3K  = 4194304;     // overlaps dead PB/BN/CP/PRAW (order-safe)
// END = 24,950,784 fl = 99.8MB (< 112.8MB proven available)

__device__ __forceinline__ float qw(float w) {
  return rintf(fminf(fmaxf(w, -1.f), 1.f));
}
__device__ __forceinline__ float4 ld4(const float* p) {
  return *reinterpret_cast<const float4*>(p);
}
__device__ __forceinline__ float tanh_c(float u) {
  const float e = __expf(2.f*u);
  return 1.f - __fdividef(2.f, e + 1.f);
}

#define MF(A,B,C) __builtin_amdgcn_mfma_f32_32x32x16_f16(A,B,C,0,0,0)

// ---------------- e-table prep: [slice][v]: f16 [0..31]=hi, [32..63]=lo*2048 ----------------
__global__ __launch_bounds__(256) void k_eprep(const float* __restrict__ emb,
                                               f16* __restrict__ ehl)
{
  const int idx = blockIdx.x*256 + threadIdx.x;     // exactly 1,310,720
  const int c = idx & 31, v = (idx >> 5) & 8191, slice = idx >> 18;
  const float val = emb[(size_t)(slice*VOCAB + v)*32 + c];
  const f16 hi = (f16)val;
  const f16 lo = (f16)((val - (float)hi)*2048.f);
  f16* row = ehl + (size_t)(slice*VOCAB + v)*64;
  row[c] = hi; row[32 + c] = lo;
}

// ---------------- w-frag prep: f16 idx = ((((slice*7+k)*2+ks)*2+hl)*64+lane)*8+j ----------------
__global__ __launch_bounds__(256) void k_wfprep(const float* __restrict__ convw,
                                                f16* __restrict__ wf)
{
  const int idx = blockIdx.x*256 + threadIdx.x;     // exactly 71,680
  const int j = idx & 7, lane = (idx >> 3) & 63, hl = (idx >> 9) & 1, ks = (idx >> 10) & 1;
  const int kk = idx >> 11, k = kk % 7, slice = kk / 7;
  const int f = lane & 31, c = ks*16 + (lane >> 5)*8 + j;
  const float val = convw[((slice*32 + f)*32 + c)*7 + k];
  const f16 hi = (f16)val;
  wf[idx] = hl ? (f16)((val - (float)hi)*2048.f) : hi;
}

// ---------------- MFMA conv: PASS 0 = stats, PASS 1 = BN1+tanh+pool ----------------
template<int PASS>
__global__ __launch_bounds__(256, 2) void k_convm(const int* __restrict__ x,
                                                  const int* __restrict__ gshift,
                                                  const float* __restrict__ ehl,    // f16 data
                                                  const float* __restrict__ wfrag,  // f16 data
                                                  const float* __restrict__ bn1,    // SoA
                                                  float* __restrict__ z,
                                                  float* __restrict__ partials)
{
  const int b = blockIdx.x;
  const int type = blockIdx.y;                      // 0..3
  const int tid = threadIdx.x;
  const int wid = tid >> 6, lane = tid & 63;
  const int lt = lane & 31, hf = lane >> 5;

  // smem: tokrow [294][34] during K-loop; thbuf[4][32][33]+poolb[3][12][2][32] in epilogue
  __shared__ float smem[9996];
  __shared__ int   tokid[294];
  __shared__ float stat[(PASS==0)?256:4];

  float* tokrow = smem;
  float* thbuf  = smem;                             // PASS1 epilogue
  float* poolb  = smem + 4224;                      // PASS1 epilogue

  const int gsv = gshift[b];
  const int NTOK = (type == 0) ? 270 : 294;

  // ---- stage token ids ----
  for (int i = tid; i < NTOK; i += 256) {
    int xs, q = i;
    if (type == 0) {
      if (i < 42)       { xs = 548; }
      else if (i < 120) { xs = 512; q = i - 42; }
      else              { xs = 440 - gsv % 12; q = i - 120; }
    } else if (type == 1) xs = 296 - gsv % 24;
    else if (type == 2)   xs = 8 - gsv % 48;
    else                  xs = 8 - gsv % 48 + 288;
    int xi = xs + q; if (xi < 0) xi += HTOT;
    tokid[i] = x[b*HTOT + xi];
  }
  __syncthreads();

  // ---- stage embedding rows (136B padded rows) ----
  for (int j = tid; j < NTOK*8; j += 256) {
    const int row = j >> 3, ch = j & 7;
    const int sl = (type == 0) ? (row < 42 ? 0 : (row < 120 ? 1 : 2)) : ((type == 1) ? 3 : 4);
    const float4 v = ld4(ehl + (size_t)(sl*VOCAB + tokid[row])*32 + ch*4);
    float* d = &tokrow[row*34 + ch*4];
    *reinterpret_cast<float2*>(d)     = make_float2(v.x, v.y);
    *reinterpret_cast<float2*>(d + 2) = make_float2(v.z, v.w);
  }
  __syncthreads();

  // ---- per-wave work assignment ----
  int slice, tb, nt, slotoff, ThV, pw, si;
  if (type == 0) {
    if      (wid == 0) { slice=0; tb=0;  nt=2; slotoff=0;   ThV=36;  pw=3;  si=0; }
    else if (wid == 1) { slice=1; tb=0;  nt=3; slotoff=42;  ThV=72;  pw=6;  si=1; }
    else if (wid == 2) { slice=2; tb=0;  nt=3; slotoff=120; ThV=144; pw=12; si=2; }
    else               { slice=2; tb=96; nt=2; slotoff=120; ThV=144; pw=12; si=2; }
  } else if (type == 1) {
    slice=3; pw=24; ThV=288; slotoff=0; si=0;
    tb = (wid == 0) ? 0 : 32 + wid*64; nt = (wid == 0) ? 3 : 2;
  } else if (type == 2) {
    slice=4; pw=48; ThV=288; slotoff=0; si=0;
    tb = (wid == 0) ? 0 : 32 + wid*64; nt = (wid == 0) ? 3 : 2;
  } else {
    slice=4; pw=48; ThV=576; slotoff=-288; si=0;
    tb = 288 + ((wid == 0) ? 0 : 32 + wid*64); nt = (wid == 0) ? 3 : 2;
  }
  const int wb = (type == 3) ? 6 : 0;

  const float* wfsl = wfrag + slice*7168;           // 7*2*2*64*8 f16 = 7168 floats per slice
  #define LDA(K,KS,HL) (*reinterpret_cast<const f16x8*>(wfsl + (((K)*2+(KS))*2+(HL))*256 + lane*4))

  f32x16 a0[3], a1[3];
  #pragma unroll
  for (int r = 0; r < 3; ++r) {
    #pragma unroll
    for (int i = 0; i < 16; ++i) { a0[r][i] = 0.f; a1[r][i] = 0.f; }
  }

  // ---- K loop ----
  // tokrow row: floats [0..15] = hi f16[c=0..31]; [16..31] = lo f16[c=0..31]
  // lane (lt,hf) B-slot k = hf*8+j -> channel:
  //   ks=0 hi: f16 hf*8+j   -> floats rp+0..3   (rp = row + hf*4)
  //   ks=1 hi: f16 16+hf*8+j-> floats rp+8..11
  //   ks=0 lo: f16 32+hf*8+j-> floats rp+16..19
  //   ks=1 lo: f16 48+hf*8+j-> floats rp+24..27
  #pragma unroll 1
  for (int k = 0; k < 7; ++k) {
    const f16x8 wh0 = LDA(k,0,0), wl0 = LDA(k,0,1), wh1 = LDA(k,1,0), wl1 = LDA(k,1,1);
    #pragma unroll
    for (int r = 0; r < 3; ++r) if (r < nt) {
      const int slot = slotoff + tb + r*32 + lt + k;
      const float* rp = tokrow + slot*34 + hf*4;
      const f16x4 q0 = *(const f16x4*)(rp),      q1 = *(const f16x4*)(rp+2);
      const f16x4 q2 = *(const f16x4*)(rp+8),    q3 = *(const f16x4*)(rp+10);
      const f16x4 q4 = *(const f16x4*)(rp+16),   q5 = *(const f16x4*)(rp+18);
      const f16x4 q6 = *(const f16x4*)(rp+24),   q7 = *(const f16x4*)(rp+26);
      const f16x8 bh0 = __builtin_shufflevector(q0,q1,0,1,2,3,4,5,6,7);
      const f16x8 bh1 = __builtin_shufflevector(q2,q3,0,1,2,3,4,5,6,7);
      const f16x8 bl0 = __builtin_shufflevector(q4,q5,0,1,2,3,4,5,6,7);
      const f16x8 bl1 = __builtin_shufflevector(q6,q7,0,1,2,3,4,5,6,7);
      a0[r] = MF(wh0, bh0, a0[r]);
      a1[r] = MF(wh0, bl0, a1[r]);
      a1[r] = MF(wl0, bh0, a1[r]);
      a0[r] = MF(wh1, bh1, a0[r]);
      a1[r] = MF(wh1, bl1, a1[r]);
      a1[r] = MF(wl1, bh1, a1[r]);
    }
  }
  __syncthreads();                                  // tokrow dead; smem becomes thbuf/poolb

  if (PASS == 1) {
    for (int i = tid; i < 2304; i += 256) poolb[i] = 0.f;
  }
  __syncthreads();

  // ---- epilogue ----
  float sv1[16], sv2[16], A1v[16], B1v[16];
  if (PASS == 0) {
    #pragma unroll
    for (int i = 0; i < 16; ++i) { sv1[i] = 0.f; sv2[i] = 0.f; }
  } else {
    #pragma unroll
    for (int i = 0; i < 16; ++i) {
      const int fr = (i&3) + 8*(i>>2) + 4*hf;
      A1v[i] = bn1[slice*32 + fr];
      B1v[i] = bn1[160 + slice*32 + fr];
    }
  }

  #pragma unroll
  for (int r = 0; r < 3; ++r) if (r < nt) {
    const int tbg = tb + r*32;
    float h[16];
    #pragma unroll
    for (int i = 0; i < 16; ++i) h[i] = a0[r][i] + a1[r][i]*(1.f/2048.f);
    if (PASS == 0) {
      const bool tv = (tbg + lt) < ThV;
      #pragma unroll
      for (int i = 0; i < 16; ++i) {
        const float hv = tv ? h[i] : 0.f;
        sv1[i] += hv; sv2[i] += hv*hv;
      }
    } else {
      #pragma unroll
      for (int i = 0; i < 16; ++i) {
        const int fr = (i&3) + 8*(i>>2) + 4*hf;
        thbuf[wid*1056 + fr*33 + lt] = tanh_c(A1v[i]*h[i] + B1v[i]);
      }
      const int tvend = min(tbg + 32, ThV);
      const int wlo = tbg / pw, whi = (tvend - 1) / pw;
      for (int w = wlo; w <= whi; ++w) {
        const int lo = max(w*pw, tbg), hi2 = min((w+1)*pw, tvend);
        float s = 0.f;
        for (int t = lo + hf; t < hi2; t += 2) s += thbuf[wid*1056 + lt*33 + (t - tbg)];
        s += __shfl_xor(s, 32);
        if (hf == 0) {
          const int piece = (w*pw < tbg) ? 1 : 0;
          poolb[(si*12 + (w - wb))*64 + piece*32 + lt] = s;
        }
      }
    }
  }

  if (PASS == 0) {
    #pragma unroll
    for (int i = 0; i < 16; ++i) {
      #pragma unroll
      for (int m = 1; m < 32; m <<= 1) {
        sv1[i] += __shfl_xor(sv1[i], m, 32);
        sv2[i] += __shfl_xor(sv2[i], m, 32);
      }
    }
    if (lt == 0) {
      #pragma unroll
      for (int i = 0; i < 16; ++i) {
        stat[wid*64 + hf*32 + i*2]     = sv1[i];
        stat[wid*64 + hf*32 + i*2 + 1] = sv2[i];
      }
    }
  }
  __syncthreads();

  // ---- combine ----
  const int nch = (type == 0) ? 96 : 32;
  if (tid < nch) {
    const int sic = tid >> 5, f = tid & 31;
    const int sg = (type == 0) ? sic : ((type == 1) ? 3 : 4);
    const int P = (sg < 4) ? sg*32 + f : ((type == 2) ? 128 + f : 160 + f);
    float s1 = 0.f, s2 = 0.f;
    if (PASS == 0) {
      const int hfc = (f >> 2) & 1, ic = (f & 3) + 4*(f >> 3);
      #pragma unroll
      for (int w = 0; w < 4; ++w) {
        const int wsi = (type == 0) ? ((w < 2) ? w : 2) : 0;
        if (wsi == sic) {
          s1 += stat[w*64 + hfc*32 + ic*2];
          s2 += stat[w*64 + hfc*32 + ic*2 + 1];
        }
      }
    } else {
      const int pwc = (type == 0) ? ((sic == 0) ? 3 : (sic == 1) ? 6 : 12)
                                  : ((type == 1) ? 24 : 48);
      const int nwin = (type >= 2) ? 6 : 12;
      const int wbc = (type == 3) ? 6 : 0;
      const float inv = 1.f/(float)pwc;
      for (int wl = 0; wl < nwin; ++wl) {
        const float p = (poolb[(sic*12 + wl)*64 + f] + poolb[(sic*12 + wl)*64 + 32 + f]) * inv;
        z[(size_t)b*1920 + sg*384 + (wl + wbc)*32 + f] = p;
        s1 += p; s2 += p*p;
      }
    }
    partials[(size_t)b*384 + P*2]     = s1;
    partials[(size_t)b*384 + P*2 + 1] = s2;
  }
}

// ---------------- BN stat reduce -> SoA {A=g*rstd, B=beta-A*m} ----------------
template<int PASS>
__global__ __launch_bounds__(256) void k_bnfinal(const float* __restrict__ partials,
                                                 const float* __restrict__ gamma,
                                                 const float* __restrict__ beta,
                                                 float* __restrict__ outAB)
{
  const int c = blockIdx.x;                        // 0..159
  const int slice = c >> 5, f = c & 31;
  const int tid = threadIdx.x;
  double s1 = 0.0, s2 = 0.0;
  for (int b = tid; b < BATCH; b += 256) {
    const float* p = partials + (size_t)b*384;
    if (slice < 4) { s1 += p[(slice*32+f)*2]; s2 += p[(slice*32+f)*2+1]; }
    else {
      s1 += (double)p[(128+f)*2]   + (double)p[(160+f)*2];
      s2 += (double)p[(128+f)*2+1] + (double)p[(160+f)*2+1];
    }
  }
  __shared__ double r1[256], r2[256];
  r1[tid] = s1; r2[tid] = s2;
  __syncthreads();
  for (int off = 128; off > 0; off >>= 1) {
    if (tid < off) { r1[tid] += r1[tid+off]; r2[tid] += r2[tid+off]; }
    __syncthreads();
  }
  if (tid == 0) {
    long N;
    if (PASS == 0) { const long Tall[5] = {36,72,144,288,576}; N = (long)BATCH * Tall[slice]; }
    else           { N = (long)BATCH * 12; }
    const double m   = r1[0]/(double)N;
    const double var = r2[0]/(double)N - m*m;
    const float rstd = (float)(1.0/sqrt(var + 1e-5));
    const float Aa = gamma[c]*rstd;
    outAB[c]       = Aa;
    outAB[160 + c] = beta[c] - Aa*(float)m;
  }
}

// ---------------- pooled BN apply + in-place f16 hi/lo pack ----------------
__global__ __launch_bounds__(256) void k_znorm(float* __restrict__ zz,
                                               const float* __restrict__ bnp)
{
  const size_t i4 = (size_t)blockIdx.x*256 + threadIdx.x;  // exactly 1,966,080
  const float4 v = ld4(zz + i4*4);
  const int j = (int)((i4*4) % 1920);
  const int slice = j / 384, f0 = j & 31;
  const float4 A = ld4(bnp + slice*32 + f0);
  const float4 B = ld4(bnp + 160 + slice*32 + f0);
  const float zn[4] = {v.x*A.x+B.x, v.y*A.y+B.y, v.z*A.z+B.z, v.w*A.w+B.w};
  uint4 pk;
  unsigned w[4];
  #pragma unroll
  for (int e = 0; e < 4; ++e) {
    const f16 hi = (f16)zn[e];
    const f16 lo = (f16)(zn[e] - (float)hi);
    w[e] = (unsigned)__builtin_bit_cast(unsigned short, hi)
         | ((unsigned)__builtin_bit_cast(unsigned short, lo) << 16);
  }
  pk.x = w[0]; pk.y = w[1]; pk.z = w[2]; pk.w = w[3];
  *reinterpret_cast<uint4*>(zz + i4*4) = pk;
}

// ---------------- weight prep ----------------
__global__ __launch_bounds__(256) void k_wprep1(const float* __restrict__ W1,
                                                f16* __restrict__ W1p)
{
  const int idx = blockIdx.x*256 + threadIdx.x;    // < 3,932,160
  const int n = idx / 1920, klds = idx - n*1920;
  const int slice = klds / 384, r = klds - slice*384;
  const int tp = r >> 5, f = r & 31;
  W1p[idx] = (f16)qw(W1[n*1920 + slice*384 + f*12 + tp]);
}

__global__ __launch_bounds__(256) void k_wprep2(const float* __restrict__ W2,
                                                f16* __restrict__ W2p)
{
  const size_t i4 = (size_t)blockIdx.x*256 + threadIdx.x;  // < 1,048,576
  const float4 v = ld4(W2 + i4*4);
  f16x4 o;
  o[0] = (f16)qw(v.x); o[1] = (f16)qw(v.y); o[2] = (f16)qw(v.z); o[3] = (f16)qw(v.w);
  *reinterpret_cast<f16x4*>(&W2p[i4*4]) = o;
}

// ---------------- MFMA GEMM: C[4096,2048] = A @ Bp^T ----------------
template<int SPLIT, int PACKED>
__global__ __launch_bounds__(256) void k_mfgemm(const f16* __restrict__ Ahi,
                                               const unsigned* __restrict__ Apk,
                                               const f16* __restrict__ Bp,
                                               float* __restrict__ C,
                                               const int K, const float oscale)
{
  __shared__ f16 sA[(SPLIT+1)*128][40];
  __shared__ f16 sB[128][40];
  const int tid = threadIdx.x;
  const int bm = blockIdx.y*128, bn = blockIdx.x*128;
  const int wid = tid >> 6, lane = tid & 63;
  const int wm = (wid >> 1)*64, wn = (wid & 1)*64;
  const int lgrp = lane >> 4, lrow = lane & 15;
  f32x4 acc[4][4];
  #pragma unroll
  for (int m = 0; m < 4; ++m)
    #pragma unroll
    for (int n = 0; n < 4; ++n) acc[m][n] = (f32x4){0.f,0.f,0.f,0.f};

  const int srow = tid >> 2, sc = (tid & 3)*8;
  for (int k0 = 0; k0 < K; k0 += 32) {
    #pragma unroll
    for (int u = 0; u < 2; ++u) {
      const int row = srow + u*64;
      if (PACKED) {
        const unsigned* ap = Apk + (size_t)(bm+row)*K + k0 + sc;
        const uint4 v0 = *reinterpret_cast<const uint4*>(ap);
        const uint4 v1 = *reinterpret_cast<const uint4*>(ap + 4);
        uint4 hi, lo;
        hi.x = (v0.x & 0xffffu) | (v0.y << 16);  hi.y = (v0.z & 0xffffu) | (v0.w << 16);
        hi.z = (v1.x & 0xffffu) | (v1.y << 16);  hi.w = (v1.z & 0xffffu) | (v1.w << 16);
        lo.x = (v0.x >> 16) | (v0.y & 0xffff0000u);  lo.y = (v0.z >> 16) | (v0.w & 0xffff0000u);
        lo.z = (v1.x >> 16) | (v1.y & 0xffff0000u);  lo.w = (v1.z >> 16) | (v1.w & 0xffff0000u);
        *reinterpret_cast<uint4*>(&sA[row][sc])     = hi;
        *reinterpret_cast<uint4*>(&sA[128+row][sc]) = lo;
      } else {
        const uint4 va = *reinterpret_cast<const uint4*>(&Ahi[(size_t)(bm+row)*K + k0 + sc]);
        *reinterpret_cast<uint4*>(&sA[row][sc]) = va;
      }
      const uint4 vb = *reinterpret_cast<const uint4*>(&Bp[(size_t)(bn+row)*K + k0 + sc]);
      *reinterpret_cast<uint4*>(&sB[row][sc]) = vb;
    }
    __syncthreads();
    f16x8 bf[4];
    #pragma unroll
    for (int n = 0; n < 4; ++n)
      bf[n] = *reinterpret_cast<const f16x8*>(&sB[wn + n*16 + lrow][lgrp*8]);
    #pragma unroll
    for (int m = 0; m < 4; ++m) {
      const f16x8 ah = *reinterpret_cast<const f16x8*>(&sA[wm + m*16 + lrow][lgrp*8]);
      #pragma unroll
      for (int n = 0; n < 4; ++n)
        acc[m][n] = __builtin_amdgcn_mfma_f32_16x16x32_f16(ah, bf[n], acc[m][n], 0, 0, 0);
      if (SPLIT) {
        const f16x8 al = *reinterpret_cast<const f16x8*>(&sA[128 + wm + m*16 + lrow][lgrp*8]);
        #pragma unroll
        for (int n = 0; n < 4; ++n)
          acc[m][n] = __builtin_amdgcn_mfma_f32_16x16x32_f16(al, bf[n], acc[m][n], 0, 0, 0);
      }
    }
    __syncthreads();
  }
  #pragma unroll
  for (int m = 0; m < 4; ++m)
    #pragma unroll
    for (int n = 0; n < 4; ++n) {
      const int col = bn + wn + n*16 + lrow;
      #pragma unroll
      for (int r = 0; r < 4; ++r)
        C[(size_t)(bm + wm + m*16 + lgrp*4 + r)*2048 + col] = acc[m][n][r]*oscale;
    }
}

// ---------------- column stats (2-stage, deterministic) ----------------
__global__ __launch_bounds__(256) void k_colpart(const float* __restrict__ Y,
                                                 double* __restrict__ part, int N)
{
  const int c0 = blockIdx.x*64;
  const int chunk = blockIdx.y;
  const int tid = threadIdx.x;
  const int c = tid & 63, rq = tid >> 6;
  double s1 = 0.0, s2 = 0.0;
  const int rbase = chunk*256;
  for (int r = rbase + rq; r < rbase+256; r += 4) {
    const float v = Y[(size_t)r*N + c0 + c];
    s1 += (double)v; s2 += (double)v*(double)v;
  }
  __shared__ double r1[256], r2[256];
  r1[tid] = s1; r2[tid] = s2;
  __syncthreads();
  if (tid < 64) {
    const double a  = r1[tid]+r1[tid+64]+r1[tid+128]+r1[tid+192];
    const double cc = r2[tid]+r2[tid+64]+r2[tid+128]+r2[tid+192];
    part[(size_t)(c0+c)*32 + chunk*2]     = a;
    part[(size_t)(c0+c)*32 + chunk*2 + 1] = cc;
  }
}

__global__ __launch_bounds__(256) void k_colfinal(const double* __restrict__ part,
                                                  const float* __restrict__ gamma,
                                                  const float* __restrict__ beta,
                                                  float* __restrict__ bnfc, int N)
{
  const int c = blockIdx.x*256 + threadIdx.x;
  if (c >= N) return;
  double s1 = 0.0, s2 = 0.0;
  #pragma unroll
  for (int ch = 0; ch < 16; ++ch) {
    s1 += part[(size_t)c*32 + ch*2];
    s2 += part[(size_t)c*32 + ch*2 + 1];
  }
  const double m   = s1/4096.0;
  const double var = s2/4096.0 - m*m;
  const float rstd = (float)(1.0/sqrt(var + 1e-5));
  const float Aa = gamma[c]*rstd;
  bnfc[c]        = Aa;
  bnfc[2048 + c] = beta[c] - Aa*(float)m;
}

// ---------------- BN + hardtanh + quantize -> integer k in f16 ----------------
__global__ __launch_bounds__(256) void k_act(const float* __restrict__ Y,
                                             const float* __restrict__ bnfc,
                                             f16* __restrict__ Zk)
{
  const size_t i4 = (size_t)blockIdx.x*256 + threadIdx.x;  // exactly 2,097,152
  const int cbase = (int)((i4*4) & 2047);
  const float4 v = ld4(Y + i4*4);
  const float4 A = ld4(bnfc + cbase);
  const float4 B = ld4(bnfc + 2048 + cbase);
  const float t[4] = {v.x*A.x+B.x, v.y*A.y+B.y, v.z*A.z+B.z, v.w*A.w+B.w};
  f16x4 o;
  #pragma unroll
  for (int e = 0; e < 4; ++e) {
    const float c = fminf(fmaxf(t[e], -1.f), 1.f);
    o[e] = (f16)rintf(c*3.f);
  }
  *reinterpret_cast<f16x4*>(&Zk[i4*4]) = o;
}

// ---------------- final dot ----------------
__global__ __launch_bounds__(256) void k_final(const f16* __restrict__ Z3,
                                               const float* __restrict__ W3,
                                               const float* __restrict__ b3,
                                               float* __restrict__ out)
{
  const int b = blockIdx.x;
  const int tid = threadIdx.x;
  float s = 0.f;
  for (int j = tid; j < 2048; j += 256)
    s += (float)Z3[(size_t)b*2048 + j] * qw(W3[j]);
  __shared__ float red[256];
  red[tid] = s;
  __syncthreads();
  for (int off = 128; off > 0; off >>= 1) {
    if (tid < off) red[tid] += red[tid+off];
    __syncthreads();
  }
  if (tid == 0) out[b] = red[0]*(1.f/3.f) + b3[0];
}

extern "C" void kernel_launch(void* const* d_in, const int* in_sizes, int n_in,
                              void* d_out, int out_size, void* d_ws, size_t ws_size,
                              hipStream_t stream)
{
  const int*   x    = (const int*)d_in[0];
  const int*   gs   = (const int*)d_in[1];
  const float* emb  = (const float*)d_in[2];
  const float* cw   = (const float*)d_in[3];
  const float* bn1g = (const float*)d_in[5];
  const float* bn1b = (const float*)d_in[6];
  const float* bnpg = (const float*)d_in[7];
  const float* bnpb = (const float*)d_in[8];
  const float* W1   = (const float*)d_in[9];
  const float* g1   = (const float*)d_in[11];
  const float* be1  = (const float*)d_in[12];
  const float* W2   = (const float*)d_in[13];
  const float* g2   = (const float*)d_in[15];
  const float* be2  = (const float*)d_in[16];
  const float* W3   = (const float*)d_in[17];
  const float* b3   = (const float*)d_in[18];
  float* ws  = (float*)d_ws;
  float* out = (float*)d_out;

  k_eprep<<<5120, 256, 0, stream>>>(emb, (f16*)(ws + OFF_EHL));
  k_wfprep<<<280, 256, 0, stream>>>(cw, (f16*)(ws + OFF_WF));

  k_convm<0><<<dim3(BATCH, 4), 256, 0, stream>>>(x, gs, ws + OFF_EHL, ws + OFF_WF,
                                                 ws + OFF_BN1, nullptr, ws + OFF_PA);
  k_bnfinal<0><<<160, 256, 0, stream>>>(ws + OFF_PA, bn1g, bn1b, ws + OFF_BN1);
  k_convm<1><<<dim3(BATCH, 4), 256, 0, stream>>>(x, gs, ws + OFF_EHL, ws + OFF_WF,
                                                 ws + OFF_BN1, ws + OFF_PRAW, ws + OFF_PB);
  k_bnfinal<1><<<160, 256, 0, stream>>>(ws + OFF_PB, bnpg, bnpb, ws + OFF_BNP);
  k_znorm<<<7680, 256, 0, stream>>>(ws + OFF_PRAW, ws + OFF_BNP);
  k_wprep1<<<15360, 256, 0, stream>>>(W1, (f16*)(ws + OFF_W1P));
  k_wprep2<<<4096, 256, 0, stream>>>(W2, (f16*)(ws + OFF_W2P));

  k_mfgemm<1,1><<<dim3(16, 32), 256, 0, stream>>>(nullptr, (const unsigned*)(ws + OFF_PRAW),
                                                  (const f16*)(ws + OFF_W1P),
                                                  ws + OFF_Y, 1920, 1.f);
  k_colpart<<<dim3(32, 16), 256, 0, stream>>>(ws + OFF_Y, (double*)(ws + OFF_CP), 2048);
  k_colfinal<<<8, 256, 0, stream>>>((const double*)(ws + OFF_CP), g1, be1, ws + OFF_BNF1, 2048);
  k_act<<<8192, 256, 0, stream>>>(ws + OFF_Y, ws + OFF_BNF1, (f16*)(ws + OFF_Z2K));

  k_mfgemm<0,0><<<dim3(16, 32), 256, 0, stream>>>((const f16*)(ws + OFF_Z2K), nullptr,
                                                  (const f16*)(ws + OFF_W2P),
                                                  ws + OFF_Y, 2048, 1.f/3.f);
  k_colpart<<<dim3(32, 16), 256, 0, stream>>>(ws + OFF_Y, (double*)(ws + OFF_CP), 2048);
  k_colfinal<<<8, 256, 0, stream>>>((const double*)(ws + OFF_CP), g2, be2, ws + OFF_BNF2, 2048);
  k_act<<<8192, 256, 0, stream>>>(ws + OFF_Y, ws + OFF_BNF2, (f16*)(ws + OFF_Z3K));

  k_final<<<4096, 256, 0, stream>>>((const f16*)(ws + OFF_Z3K), W3, b3, out);
}

// Round 6
// 886.442 us; speedup vs baseline: 4.3082x; 1.0245x over previous
//
#include <hip/hip_runtime.h>
#include <cmath>

#define HTOT  590
#define BATCH 4096
#define VOCAB 8192

typedef _Float16 f16;
typedef __attribute__((ext_vector_type(8))) _Float16 f16x8;
typedef __attribute__((ext_vector_type(4))) _Float16 f16x4;
typedef __attribute__((ext_vector_type(4))) float f32x4;
typedef __attribute__((ext_vector_type(16))) float f32x16;

// ---------------- workspace layout (float units) ----------------
constexpr size_t OFF_EHL  = 0;           // 1,310,720 fl: e hi/lo f16 [5][8192][64f16]
constexpr size_t OFF_WF   = 1310720;     // 35,840 fl: wfrag f16 [5][7][2][2][64][8]
constexpr size_t OFF_PA   = 1347584;     // 1,572,864: [b][192][2] pass-A stats
constexpr size_t OFF_PB   = 2921472;     // 1,572,864: [b][192][2] pooled stats
constexpr size_t OFF_BN1  = 4494336;     // 320 (SoA A[160], B[160])
constexpr size_t OFF_BNP  = 4494656;     // 320
constexpr size_t OFF_CP   = 4494976;     // 131,072 (2048*16*2 doubles)
constexpr size_t OFF_BNF1 = 4626048;     // 4,096
constexpr size_t OFF_PRAW = 4630528;     // 7,864,320: p fp32 -> packed {hi,lo} f16 in place
constexpr size_t OFF_W1P  = 12494848;    // 1,966,080 (f16)
constexpr size_t OFF_W2P  = 14460928;    // 2,097,152 (f16)
constexpr size_t OFF_Y    = 16558080;    // 8,388,608
constexpr size_t OFF_BNF2 = 24946688;    // 4,096
constexpr size_t OFF_Z2K  = 0;           // conv-region dead by then
constexpr size_t OFF_Z3K  = 4194304;     // overlaps dead PB/BN/CP/PRAW (order-safe)
// END = 24,950,784 fl = 99.8MB (< 112.8MB proven available)

__device__ __forceinline__ float qw(float w) {
  return rintf(fminf(fmaxf(w, -1.f), 1.f));
}
__device__ __forceinline__ float4 ld4(const float* p) {
  return *reinterpret_cast<const float4*>(p);
}
__device__ __forceinline__ float tanh_c(float u) {
  const float e = __expf(2.f*u);
  return 1.f - __fdividef(2.f, e + 1.f);
}

#define MF(A,B,C) __builtin_amdgcn_mfma_f32_32x32x16_f16(A,B,C,0,0,0)

// ---------------- e-table prep: [slice][v]: f16 [0..31]=hi, [32..63]=lo*2048 ----------------
__global__ __launch_bounds__(256) void k_eprep(const float* __restrict__ emb,
                                               f16* __restrict__ ehl)
{
  const int idx = blockIdx.x*256 + threadIdx.x;     // exactly 1,310,720
  const int c = idx & 31, v = (idx >> 5) & 8191, slice = idx >> 18;
  const float val = emb[(size_t)(slice*VOCAB + v)*32 + c];
  const f16 hi = (f16)val;
  const f16 lo = (f16)((val - (float)hi)*2048.f);
  f16* row = ehl + (size_t)(slice*VOCAB + v)*64;
  row[c] = hi; row[32 + c] = lo;
}

// ---------------- w-frag prep: f16 idx = ((((slice*7+k)*2+ks)*2+hl)*64+lane)*8+j ----------------
__global__ __launch_bounds__(256) void k_wfprep(const float* __restrict__ convw,
                                                f16* __restrict__ wf)
{
  const int idx = blockIdx.x*256 + threadIdx.x;     // exactly 71,680
  const int j = idx & 7, lane = (idx >> 3) & 63, hl = (idx >> 9) & 1, ks = (idx >> 10) & 1;
  const int kk = idx >> 11, k = kk % 7, slice = kk / 7;
  const int f = lane & 31, c = ks*16 + (lane >> 5)*8 + j;
  const float val = convw[((slice*32 + f)*32 + c)*7 + k];
  const f16 hi = (f16)val;
  wf[idx] = hl ? (f16)((val - (float)hi)*2048.f) : hi;
}

// ---------------- MFMA conv: PASS 0 = stats, PASS 1 = BN1+tanh+pool ----------------
template<int PASS>
__global__ __launch_bounds__(256, 2) void k_convm(const int* __restrict__ x,
                                                  const int* __restrict__ gshift,
                                                  const float* __restrict__ ehl,    // f16 data
                                                  const float* __restrict__ wfrag,  // f16 data
                                                  const float* __restrict__ bn1,    // SoA
                                                  float* __restrict__ z,
                                                  float* __restrict__ partials)
{
  const int b = blockIdx.x;
  const int type = blockIdx.y;                      // 0..3
  const int tid = threadIdx.x;
  const int wid = tid >> 6, lane = tid & 63;
  const int lt = lane & 31, hf = lane >> 5;

  // smem: tokrow [294][36] during K-loop (rows 144B, 16B-aligned);
  //       thbuf[4][32][33] + poolb[3][12][2][32] in PASS1 epilogue
  __shared__ float smem[10584];
  __shared__ int   tokid[294];
  __shared__ float stat[(PASS==0)?256:4];

  float* tokrow = smem;
  float* thbuf  = smem;                             // PASS1 epilogue
  float* poolb  = smem + 4224;                      // PASS1 epilogue

  const int gsv = gshift[b];
  const int NTOK = (type == 0) ? 270 : 294;

  // ---- stage token ids ----
  for (int i = tid; i < NTOK; i += 256) {
    int xs, q = i;
    if (type == 0) {
      if (i < 42)       { xs = 548; }
      else if (i < 120) { xs = 512; q = i - 42; }
      else              { xs = 440 - gsv % 12; q = i - 120; }
    } else if (type == 1) xs = 296 - gsv % 24;
    else if (type == 2)   xs = 8 - gsv % 48;
    else                  xs = 8 - gsv % 48 + 288;
    int xi = xs + q; if (xi < 0) xi += HTOT;
    tokid[i] = x[b*HTOT + xi];
  }
  __syncthreads();

  // ---- stage embedding rows: 16B chunks into 144B-aligned rows ----
  for (int j = tid; j < NTOK*8; j += 256) {
    const int row = j >> 3, ch = j & 7;
    const int sl = (type == 0) ? (row < 42 ? 0 : (row < 120 ? 1 : 2)) : ((type == 1) ? 3 : 4);
    const float4 v = ld4(ehl + (size_t)(sl*VOCAB + tokid[row])*32 + ch*4);
    *reinterpret_cast<float4*>(&tokrow[row*36 + ch*4]) = v;
  }
  __syncthreads();

  // ---- per-wave work assignment ----
  int slice, tb, nt, slotoff, ThV, pw, si;
  if (type == 0) {
    if      (wid == 0) { slice=0; tb=0;  nt=2; slotoff=0;   ThV=36;  pw=3;  si=0; }
    else if (wid == 1) { slice=1; tb=0;  nt=3; slotoff=42;  ThV=72;  pw=6;  si=1; }
    else if (wid == 2) { slice=2; tb=0;  nt=3; slotoff=120; ThV=144; pw=12; si=2; }
    else               { slice=2; tb=96; nt=2; slotoff=120; ThV=144; pw=12; si=2; }
  } else if (type == 1) {
    slice=3; pw=24; ThV=288; slotoff=0; si=0;
    tb = (wid == 0) ? 0 : 32 + wid*64; nt = (wid == 0) ? 3 : 2;
  } else if (type == 2) {
    slice=4; pw=48; ThV=288; slotoff=0; si=0;
    tb = (wid == 0) ? 0 : 32 + wid*64; nt = (wid == 0) ? 3 : 2;
  } else {
    slice=4; pw=48; ThV=576; slotoff=-288; si=0;
    tb = 288 + ((wid == 0) ? 0 : 32 + wid*64); nt = (wid == 0) ? 3 : 2;
  }
  const int wb = (type == 3) ? 6 : 0;

  const float* wfsl = wfrag + slice*7168;           // 7*2*2*64*8 f16 = 7168 floats per slice
  #define LDA(K,KS,HL) (*reinterpret_cast<const f16x8*>(wfsl + (((K)*2+(KS))*2+(HL))*256 + lane*4))

  f32x16 a0[3], a1[3];
  #pragma unroll
  for (int r = 0; r < 3; ++r) {
    #pragma unroll
    for (int i = 0; i < 16; ++i) { a0[r][i] = 0.f; a1[r][i] = 0.f; }
  }

  // ---- K loop ----
  // tokrow row (36 fl, 144B): floats [0..15]=hi f16[c0..31]; [16..31]=lo.
  // Lane (lt,hf): fragment classes are 16B-contiguous at rp = row*36 + hf*4:
  //   bh0 @ +0, bh1 @ +8, bl0 @ +16, bl1 @ +24 (floats) -> single ds_read_b128 each.
  const float* p0 = tokrow + (size_t)(slotoff + tb + lt)*36 + hf*4;
  const float* p1 = p0 + 1152;                      // +32 rows
  const float* p2 = p0 + 2304;                      // +64 rows
  f16x8 wh0 = LDA(0,0,0), wl0 = LDA(0,0,1), wh1 = LDA(0,1,0), wl1 = LDA(0,1,1);
  #pragma unroll 1
  for (int k = 0; k < 7; ++k) {
    f16x8 nh0, nl0, nh1, nl1;
    if (k < 6) { nh0 = LDA(k+1,0,0); nl0 = LDA(k+1,0,1); nh1 = LDA(k+1,1,0); nl1 = LDA(k+1,1,1); }
    {
      const f16x8 bh0 = *(const f16x8*)(p0),    bh1 = *(const f16x8*)(p0+8);
      const f16x8 bl0 = *(const f16x8*)(p0+16), bl1 = *(const f16x8*)(p0+24);
      a0[0]=MF(wh0,bh0,a0[0]); a1[0]=MF(wh0,bl0,a1[0]); a1[0]=MF(wl0,bh0,a1[0]);
      a0[0]=MF(wh1,bh1,a0[0]); a1[0]=MF(wh1,bl1,a1[0]); a1[0]=MF(wl1,bh1,a1[0]);
    }
    if (nt > 1) {
      const f16x8 bh0 = *(const f16x8*)(p1),    bh1 = *(const f16x8*)(p1+8);
      const f16x8 bl0 = *(const f16x8*)(p1+16), bl1 = *(const f16x8*)(p1+24);
      a0[1]=MF(wh0,bh0,a0[1]); a1[1]=MF(wh0,bl0,a1[1]); a1[1]=MF(wl0,bh0,a1[1]);
      a0[1]=MF(wh1,bh1,a0[1]); a1[1]=MF(wh1,bl1,a1[1]); a1[1]=MF(wl1,bh1,a1[1]);
    }
    if (nt > 2) {
      const f16x8 bh0 = *(const f16x8*)(p2),    bh1 = *(const f16x8*)(p2+8);
      const f16x8 bl0 = *(const f16x8*)(p2+16), bl1 = *(const f16x8*)(p2+24);
      a0[2]=MF(wh0,bh0,a0[2]); a1[2]=MF(wh0,bl0,a1[2]); a1[2]=MF(wl0,bh0,a1[2]);
      a0[2]=MF(wh1,bh1,a0[2]); a1[2]=MF(wh1,bl1,a1[2]); a1[2]=MF(wl1,bh1,a1[2]);
    }
    p0 += 36; p1 += 36; p2 += 36;
    wh0 = nh0; wl0 = nl0; wh1 = nh1; wl1 = nl1;
  }
  __syncthreads();                                  // tokrow dead; smem becomes thbuf/poolb

  if (PASS == 1) {
    for (int i = tid; i < 2304; i += 256) poolb[i] = 0.f;
  }
  __syncthreads();

  // ---- epilogue ----
  float sv1[16], sv2[16], A1v[16], B1v[16];
  if (PASS == 0) {
    #pragma unroll
    for (int i = 0; i < 16; ++i) { sv1[i] = 0.f; sv2[i] = 0.f; }
  } else {
    #pragma unroll
    for (int i = 0; i < 16; ++i) {
      const int fr = (i&3) + 8*(i>>2) + 4*hf;
      A1v[i] = bn1[slice*32 + fr];
      B1v[i] = bn1[160 + slice*32 + fr];
    }
  }

  #pragma unroll
  for (int r = 0; r < 3; ++r) if (r < nt) {
    const int tbg = tb + r*32;
    float h[16];
    #pragma unroll
    for (int i = 0; i < 16; ++i) h[i] = a0[r][i] + a1[r][i]*(1.f/2048.f);
    if (PASS == 0) {
      const bool tv = (tbg + lt) < ThV;
      #pragma unroll
      for (int i = 0; i < 16; ++i) {
        const float hv = tv ? h[i] : 0.f;
        sv1[i] += hv; sv2[i] += hv*hv;
      }
    } else {
      #pragma unroll
      for (int i = 0; i < 16; ++i) {
        const int fr = (i&3) + 8*(i>>2) + 4*hf;
        thbuf[wid*1056 + fr*33 + lt] = tanh_c(A1v[i]*h[i] + B1v[i]);
      }
      const int tvend = min(tbg + 32, ThV);
      const int wlo = tbg / pw, whi = (tvend - 1) / pw;
      for (int w = wlo; w <= whi; ++w) {
        const int lo = max(w*pw, tbg), hi2 = min((w+1)*pw, tvend);
        float s = 0.f;
        for (int t = lo + hf; t < hi2; t += 2) s += thbuf[wid*1056 + lt*33 + (t - tbg)];
        s += __shfl_xor(s, 32);
        if (hf == 0) {
          const int piece = (w*pw < tbg) ? 1 : 0;
          poolb[(si*12 + (w - wb))*64 + piece*32 + lt] = s;
        }
      }
    }
  }

  if (PASS == 0) {
    #pragma unroll
    for (int i = 0; i < 16; ++i) {
      #pragma unroll
      for (int m = 1; m < 32; m <<= 1) {
        sv1[i] += __shfl_xor(sv1[i], m, 32);
        sv2[i] += __shfl_xor(sv2[i], m, 32);
      }
    }
    if (lt == 0) {
      #pragma unroll
      for (int i = 0; i < 16; ++i) {
        stat[wid*64 + hf*32 + i*2]     = sv1[i];
        stat[wid*64 + hf*32 + i*2 + 1] = sv2[i];
      }
    }
  }
  __syncthreads();

  // ---- combine ----
  const int nch = (type == 0) ? 96 : 32;
  if (tid < nch) {
    const int sic = tid >> 5, f = tid & 31;
    const int sg = (type == 0) ? sic : ((type == 1) ? 3 : 4);
    const int P = (sg < 4) ? sg*32 + f : ((type == 2) ? 128 + f : 160 + f);
    float s1 = 0.f, s2 = 0.f;
    if (PASS == 0) {
      const int hfc = (f >> 2) & 1, ic = (f & 3) + 4*(f >> 3);
      #pragma unroll
      for (int w = 0; w < 4; ++w) {
        const int wsi = (type == 0) ? ((w < 2) ? w : 2) : 0;
        if (wsi == sic) {
          s1 += stat[w*64 + hfc*32 + ic*2];
          s2 += stat[w*64 + hfc*32 + ic*2 + 1];
        }
      }
    } else {
      const int pwc = (type == 0) ? ((sic == 0) ? 3 : (sic == 1) ? 6 : 12)
                                  : ((type == 1) ? 24 : 48);
      const int nwin = (type >= 2) ? 6 : 12;
      const int wbc = (type == 3) ? 6 : 0;
      const float inv = 1.f/(float)pwc;
      for (int wl = 0; wl < nwin; ++wl) {
        const float p = (poolb[(sic*12 + wl)*64 + f] + poolb[(sic*12 + wl)*64 + 32 + f]) * inv;
        z[(size_t)b*1920 + sg*384 + (wl + wbc)*32 + f] = p;
        s1 += p; s2 += p*p;
      }
    }
    partials[(size_t)b*384 + P*2]     = s1;
    partials[(size_t)b*384 + P*2 + 1] = s2;
  }
}

// ---------------- BN stat reduce -> SoA {A=g*rstd, B=beta-A*m} ----------------
template<int PASS>
__global__ __launch_bounds__(256) void k_bnfinal(const float* __restrict__ partials,
                                                 const float* __restrict__ gamma,
                                                 const float* __restrict__ beta,
                                                 float* __restrict__ outAB)
{
  const int c = blockIdx.x;                        // 0..159
  const int slice = c >> 5, f = c & 31;
  const int tid = threadIdx.x;
  double s1 = 0.0, s2 = 0.0;
  for (int b = tid; b < BATCH; b += 256) {
    const float* p = partials + (size_t)b*384;
    if (slice < 4) { s1 += p[(slice*32+f)*2]; s2 += p[(slice*32+f)*2+1]; }
    else {
      s1 += (double)p[(128+f)*2]   + (double)p[(160+f)*2];
      s2 += (double)p[(128+f)*2+1] + (double)p[(160+f)*2+1];
    }
  }
  __shared__ double r1[256], r2[256];
  r1[tid] = s1; r2[tid] = s2;
  __syncthreads();
  for (int off = 128; off > 0; off >>= 1) {
    if (tid < off) { r1[tid] += r1[tid+off]; r2[tid] += r2[tid+off]; }
    __syncthreads();
  }
  if (tid == 0) {
    long N;
    if (PASS == 0) { const long Tall[5] = {36,72,144,288,576}; N = (long)BATCH * Tall[slice]; }
    else           { N = (long)BATCH * 12; }
    const double m   = r1[0]/(double)N;
    const double var = r2[0]/(double)N - m*m;
    const float rstd = (float)(1.0/sqrt(var + 1e-5));
    const float Aa = gamma[c]*rstd;
    outAB[c]       = Aa;
    outAB[160 + c] = beta[c] - Aa*(float)m;
  }
}

// ---------------- pooled BN apply + in-place f16 hi/lo pack ----------------
__global__ __launch_bounds__(256) void k_znorm(float* __restrict__ zz,
                                               const float* __restrict__ bnp)
{
  const size_t i4 = (size_t)blockIdx.x*256 + threadIdx.x;  // exactly 1,966,080
  const float4 v = ld4(zz + i4*4);
  const int j = (int)((i4*4) % 1920);
  const int slice = j / 384, f0 = j & 31;
  const float4 A = ld4(bnp + slice*32 + f0);
  const float4 B = ld4(bnp + 160 + slice*32 + f0);
  const float zn[4] = {v.x*A.x+B.x, v.y*A.y+B.y, v.z*A.z+B.z, v.w*A.w+B.w};
  uint4 pk;
  unsigned w[4];
  #pragma unroll
  for (int e = 0; e < 4; ++e) {
    const f16 hi = (f16)zn[e];
    const f16 lo = (f16)(zn[e] - (float)hi);
    w[e] = (unsigned)__builtin_bit_cast(unsigned short, hi)
         | ((unsigned)__builtin_bit_cast(unsigned short, lo) << 16);
  }
  pk.x = w[0]; pk.y = w[1]; pk.z = w[2]; pk.w = w[3];
  *reinterpret_cast<uint4*>(zz + i4*4) = pk;
}

// ---------------- weight prep ----------------
__global__ __launch_bounds__(256) void k_wprep1(const float* __restrict__ W1,
                                                f16* __restrict__ W1p)
{
  const int idx = blockIdx.x*256 + threadIdx.x;    // < 3,932,160
  const int n = idx / 1920, klds = idx - n*1920;
  const int slice = klds / 384, r = klds - slice*384;
  const int tp = r >> 5, f = r & 31;
  W1p[idx] = (f16)qw(W1[n*1920 + slice*384 + f*12 + tp]);
}

__global__ __launch_bounds__(256) void k_wprep2(const float* __restrict__ W2,
                                                f16* __restrict__ W2p)
{
  const size_t i4 = (size_t)blockIdx.x*256 + threadIdx.x;  // < 1,048,576
  const float4 v = ld4(W2 + i4*4);
  f16x4 o;
  o[0] = (f16)qw(v.x); o[1] = (f16)qw(v.y); o[2] = (f16)qw(v.z); o[3] = (f16)qw(v.w);
  *reinterpret_cast<f16x4*>(&W2p[i4*4]) = o;
}

// ---------------- MFMA GEMM: C[4096,2048] = A @ Bp^T ----------------
template<int SPLIT, int PACKED>
__global__ __launch_bounds__(256) void k_mfgemm(const f16* __restrict__ Ahi,
                                               const unsigned* __restrict__ Apk,
                                               const f16* __restrict__ Bp,
                                               float* __restrict__ C,
                                               const int K, const float oscale)
{
  __shared__ f16 sA[(SPLIT+1)*128][40];
  __shared__ f16 sB[128][40];
  const int tid = threadIdx.x;
  const int bm = blockIdx.y*128, bn = blockIdx.x*128;
  const int wid = tid >> 6, lane = tid & 63;
  const int wm = (wid >> 1)*64, wn = (wid & 1)*64;
  const int lgrp = lane >> 4, lrow = lane & 15;
  f32x4 acc[4][4];
  #pragma unroll
  for (int m = 0; m < 4; ++m)
    #pragma unroll
    for (int n = 0; n < 4; ++n) acc[m][n] = (f32x4){0.f,0.f,0.f,0.f};

  const int srow = tid >> 2, sc = (tid & 3)*8;
  for (int k0 = 0; k0 < K; k0 += 32) {
    #pragma unroll
    for (int u = 0; u < 2; ++u) {
      const int row = srow + u*64;
      if (PACKED) {
        const unsigned* ap = Apk + (size_t)(bm+row)*K + k0 + sc;
        const uint4 v0 = *reinterpret_cast<const uint4*>(ap);
        const uint4 v1 = *reinterpret_cast<const uint4*>(ap + 4);
        uint4 hi, lo;
        hi.x = (v0.x & 0xffffu) | (v0.y << 16);  hi.y = (v0.z & 0xffffu) | (v0.w << 16);
        hi.z = (v1.x & 0xffffu) | (v1.y << 16);  hi.w = (v1.z & 0xffffu) | (v1.w << 16);
        lo.x = (v0.x >> 16) | (v0.y & 0xffff0000u);  lo.y = (v0.z >> 16) | (v0.w & 0xffff0000u);
        lo.z = (v1.x >> 16) | (v1.y & 0xffff0000u);  lo.w = (v1.z >> 16) | (v1.w & 0xffff0000u);
        *reinterpret_cast<uint4*>(&sA[row][sc])     = hi;
        *reinterpret_cast<uint4*>(&sA[128+row][sc]) = lo;
      } else {
        const uint4 va = *reinterpret_cast<const uint4*>(&Ahi[(size_t)(bm+row)*K + k0 + sc]);
        *reinterpret_cast<uint4*>(&sA[row][sc]) = va;
      }
      const uint4 vb = *reinterpret_cast<const uint4*>(&Bp[(size_t)(bn+row)*K + k0 + sc]);
      *reinterpret_cast<uint4*>(&sB[row][sc]) = vb;
    }
    __syncthreads();
    f16x8 bf[4];
    #pragma unroll
    for (int n = 0; n < 4; ++n)
      bf[n] = *reinterpret_cast<const f16x8*>(&sB[wn + n*16 + lrow][lgrp*8]);
    #pragma unroll
    for (int m = 0; m < 4; ++m) {
      const f16x8 ah = *reinterpret_cast<const f16x8*>(&sA[wm + m*16 + lrow][lgrp*8]);
      #pragma unroll
      for (int n = 0; n < 4; ++n)
        acc[m][n] = __builtin_amdgcn_mfma_f32_16x16x32_f16(ah, bf[n], acc[m][n], 0, 0, 0);
      if (SPLIT) {
        const f16x8 al = *reinterpret_cast<const f16x8*>(&sA[128 + wm + m*16 + lrow][lgrp*8]);
        #pragma unroll
        for (int n = 0; n < 4; ++n)
          acc[m][n] = __builtin_amdgcn_mfma_f32_16x16x32_f16(al, bf[n], acc[m][n], 0, 0, 0);
      }
    }
    __syncthreads();
  }
  #pragma unroll
  for (int m = 0; m < 4; ++m)
    #pragma unroll
    for (int n = 0; n < 4; ++n) {
      const int col = bn + wn + n*16 + lrow;
      #pragma unroll
      for (int r = 0; r < 4; ++r)
        C[(size_t)(bm + wm + m*16 + lgrp*4 + r)*2048 + col] = acc[m][n][r]*oscale;
    }
}

// ---------------- column stats (2-stage, deterministic) ----------------
__global__ __launch_bounds__(256) void k_colpart(const float* __restrict__ Y,
                                                 double* __restrict__ part, int N)
{
  const int c0 = blockIdx.x*64;
  const int chunk = blockIdx.y;
  const int tid = threadIdx.x;
  const int c = tid & 63, rq = tid >> 6;
  double s1 = 0.0, s2 = 0.0;
  const int rbase = chunk*256;
  for (int r = rbase + rq; r < rbase+256; r += 4) {
    const float v = Y[(size_t)r*N + c0 + c];
    s1 += (double)v; s2 += (double)v*(double)v;
  }
  __shared__ double r1[256], r2[256];
  r1[tid] = s1; r2[tid] = s2;
  __syncthreads();
  if (tid < 64) {
    const double a  = r1[tid]+r1[tid+64]+r1[tid+128]+r1[tid+192];
    const double cc = r2[tid]+r2[tid+64]+r2[tid+128]+r2[tid+192];
    part[(size_t)(c0+c)*32 + chunk*2]     = a;
    part[(size_t)(c0+c)*32 + chunk*2 + 1] = cc;
  }
}

__global__ __launch_bounds__(256) void k_colfinal(const double* __restrict__ part,
                                                  const float* __restrict__ gamma,
                                                  const float* __restrict__ beta,
                                                  float* __restrict__ bnfc, int N)
{
  const int c = blockIdx.x*256 + threadIdx.x;
  if (c >= N) return;
  double s1 = 0.0, s2 = 0.0;
  #pragma unroll
  for (int ch = 0; ch < 16; ++ch) {
    s1 += part[(size_t)c*32 + ch*2];
    s2 += part[(size_t)c*32 + ch*2 + 1];
  }
  const double m   = s1/4096.0;
  const double var = s2/4096.0 - m*m;
  const float rstd = (float)(1.0/sqrt(var + 1e-5));
  const float Aa = gamma[c]*rstd;
  bnfc[c]        = Aa;
  bnfc[2048 + c] = beta[c] - Aa*(float)m;
}

// ---------------- BN + hardtanh + quantize -> integer k in f16 ----------------
__global__ __launch_bounds__(256) void k_act(const float* __restrict__ Y,
                                             const float* __restrict__ bnfc,
                                             f16* __restrict__ Zk)
{
  const size_t i4 = (size_t)blockIdx.x*256 + threadIdx.x;  // exactly 2,097,152
  const int cbase = (int)((i4*4) & 2047);
  const float4 v = ld4(Y + i4*4);
  const float4 A = ld4(bnfc + cbase);
  const float4 B = ld4(bnfc + 2048 + cbase);
  const float t[4] = {v.x*A.x+B.x, v.y*A.y+B.y, v.z*A.z+B.z, v.w*A.w+B.w};
  f16x4 o;
  #pragma unroll
  for (int e = 0; e < 4; ++e) {
    const float c = fminf(fmaxf(t[e], -1.f), 1.f);
    o[e] = (f16)rintf(c*3.f);
  }
  *reinterpret_cast<f16x4*>(&Zk[i4*4]) = o;
}

// ---------------- final dot ----------------
__global__ __launch_bounds__(256) void k_final(const f16* __restrict__ Z3,
                                               const float* __restrict__ W3,
                                               const float* __restrict__ b3,
                                               float* __restrict__ out)
{
  const int b = blockIdx.x;
  const int tid = threadIdx.x;
  float s = 0.f;
  for (int j = tid; j < 2048; j += 256)
    s += (float)Z3[(size_t)b*2048 + j] * qw(W3[j]);
  __shared__ float red[256];
  red[tid] = s;
  __syncthreads();
  for (int off = 128; off > 0; off >>= 1) {
    if (tid < off) red[tid] += red[tid+off];
    __syncthreads();
  }
  if (tid == 0) out[b] = red[0]*(1.f/3.f) + b3[0];
}

extern "C" void kernel_launch(void* const* d_in, const int* in_sizes, int n_in,
                              void* d_out, int out_size, void* d_ws, size_t ws_size,
                              hipStream_t stream)
{
  const int*   x    = (const int*)d_in[0];
  const int*   gs   = (const int*)d_in[1];
  const float* emb  = (const float*)d_in[2];
  const float* cw   = (const float*)d_in[3];
  const float* bn1g = (const float*)d_in[5];
  const float* bn1b = (const float*)d_in[6];
  const float* bnpg = (const float*)d_in[7];
  const float* bnpb = (const float*)d_in[8];
  const float* W1   = (const float*)d_in[9];
  const float* g1   = (const float*)d_in[11];
  const float* be1  = (const float*)d_in[12];
  const float* W2   = (const float*)d_in[13];
  const float* g2   = (const float*)d_in[15];
  const float* be2  = (const float*)d_in[16];
  const float* W3   = (const float*)d_in[17];
  const float* b3   = (const float*)d_in[18];
  float* ws  = (float*)d_ws;
  float* out = (float*)d_out;

  k_eprep<<<5120, 256, 0, stream>>>(emb, (f16*)(ws + OFF_EHL));
  k_wfprep<<<280, 256, 0, stream>>>(cw, (f16*)(ws + OFF_WF));

  k_convm<0><<<dim3(BATCH, 4), 256, 0, stream>>>(x, gs, ws + OFF_EHL, ws + OFF_WF,
                                                 ws + OFF_BN1, nullptr, ws + OFF_PA);
  k_bnfinal<0><<<160, 256, 0, stream>>>(ws + OFF_PA, bn1g, bn1b, ws + OFF_BN1);
  k_convm<1><<<dim3(BATCH, 4), 256, 0, stream>>>(x, gs, ws + OFF_EHL, ws + OFF_WF,
                                                 ws + OFF_BN1, ws + OFF_PRAW, ws + OFF_PB);
  k_bnfinal<1><<<160, 256, 0, stream>>>(ws + OFF_PB, bnpg, bnpb, ws + OFF_BNP);
  k_znorm<<<7680, 256, 0, stream>>>(ws + OFF_PRAW, ws + OFF_BNP);
  k_wprep1<<<15360, 256, 0, stream>>>(W1, (f16*)(ws + OFF_W1P));
  k_wprep2<<<4096, 256, 0, stream>>>(W2, (f16*)(ws + OFF_W2P));

  k_mfgemm<1,1><<<dim3(16, 32), 256, 0, stream>>>(nullptr, (const unsigned*)(ws + OFF_PRAW),
                                                  (const f16*)(ws + OFF_W1P),
                                                  ws + OFF_Y, 1920, 1.f);
  k_colpart<<<dim3(32, 16), 256, 0, stream>>>(ws + OFF_Y, (double*)(ws + OFF_CP), 2048);
  k_colfinal<<<8, 256, 0, stream>>>((const double*)(ws + OFF_CP), g1, be1, ws + OFF_BNF1, 2048);
  k_act<<<8192, 256, 0, stream>>>(ws + OFF_Y, ws + OFF_BNF1, (f16*)(ws + OFF_Z2K));

  k_mfgemm<0,0><<<dim3(16, 32), 256, 0, stream>>>((const f16*)(ws + OFF_Z2K), nullptr,
                                                  (const f16*)(ws + OFF_W2P),
                                                  ws + OFF_Y, 2048, 1.f/3.f);
  k_colpart<<<dim3(32, 16), 256, 0, stream>>>(ws + OFF_Y, (double*)(ws + OFF_CP), 2048);
  k_colfinal<<<8, 256, 0, stream>>>((const double*)(ws + OFF_CP), g2, be2, ws + OFF_BNF2, 2048);
  k_act<<<8192, 256, 0, stream>>>(ws + OFF_Y, ws + OFF_BNF2, (f16*)(ws + OFF_Z3K));

  k_final<<<4096, 256, 0, stream>>>((const f16*)(ws + OFF_Z3K), W3, b3, out);
}